// Round 7
// baseline (818.209 us; speedup 1.0000x reference)
//
#include <hip/hip_runtime.h>
#include <stdint.h>

// ---------------------------------------------------------------------------
// ErrorCorrectionModule on MI355X (gfx950)
// B=2, L=2048, H=1024, NH=16, HD=64, M=1024, SCALES=(1,2,4)
// R6: attn VALU cut — exp2-domain softmax (0.125*log2e folded into Q GEMM
// epilogue as a per-column post-scale) + EXACT defer-rescale
// (skip acc/lS rescale when __all(tmax <= m); v_exp_f32(0)==1.0 so the
// non-skip path is bit-identical for lanes whose max didn't grow).
// f2bf RNE packing retained (R2's cvt_pk asm remains excluded).
// Rest identical to R4 (passed, 813 us, absmax 0.0156).
// ---------------------------------------------------------------------------

#define MiBc ((size_t)1 << 20)

using s16x8 = __attribute__((ext_vector_type(8))) short;   // 8 bf16 (4 VGPR)
using s16x4 = __attribute__((ext_vector_type(4))) short;   // 4 bf16 (2 VGPR)
using u16x4 = __attribute__((ext_vector_type(4))) unsigned short;
using f32x4 = __attribute__((ext_vector_type(4))) float;

__device__ __forceinline__ uint16_t f2bf(float f) {
  uint32_t u = __float_as_uint(f);
  return (uint16_t)((u + 0x7fffu + ((u >> 16) & 1u)) >> 16);  // RNE
}

__device__ __forceinline__ float fexp2(float x) {
  return __builtin_amdgcn_exp2f(x);  // raw v_exp_f32 (2^x)
}

// async global->LDS, 16B per lane; LDS dest is wave-uniform base + lane*16
__device__ __forceinline__ void load_lds16(const uint16_t* g, uint16_t* l) {
  __builtin_amdgcn_global_load_lds(
      (const __attribute__((address_space(1))) void*)(const void*)g,
      (__attribute__((address_space(3))) void*)(void*)l, 16, 0, 0);
}

// ---------------------------------------------------------------------------
// Transpose fp32 [R][C] -> bf16 [C][R]  (B^T weight layout builder)
// ---------------------------------------------------------------------------
struct TD { const float* in; uint16_t* out; };
struct TD14 { TD d[14]; };

__global__ __launch_bounds__(256) void k_transpose(TD14 ds, int R, int C) {
  const float* in = ds.d[blockIdx.y].in;
  uint16_t* out = ds.d[blockIdx.y].out;
  const int nTC = C >> 5;
  const int bi = blockIdx.x / nTC, bj = blockIdx.x % nTC;
  __shared__ float t[32][33];
  const int tx = threadIdx.x & 31, ty = threadIdx.x >> 5;  // ty 0..7
#pragma unroll
  for (int p = 0; p < 4; ++p) {
    int r = bi * 32 + ty + p * 8;
    t[ty + p * 8][tx] = in[(size_t)r * C + bj * 32 + tx];
  }
  __syncthreads();
#pragma unroll
  for (int p = 0; p < 4; ++p) {
    int c = bj * 32 + ty + p * 8;
    out[(size_t)c * R + bi * 32 + tx] = f2bf(t[tx][ty + p * 8]);
  }
}

// plain fp32 -> bf16 convert (error_memory, kept row-major for sim's B^T)
__global__ __launch_bounds__(256) void k_f2bf4(const float* __restrict__ in,
                                               uint16_t* __restrict__ out) {
  int i = (blockIdx.x * 256 + threadIdx.x) * 4;
  float4 v = *(const float4*)(in + i);
  u16x4 o = {f2bf(v.x), f2bf(v.y), f2bf(v.z), f2bf(v.w)};
  *(u16x4*)(out + i) = o;
}

// pack bq|bk|bv (3 scales) into BQKV[3][3072]
__global__ __launch_bounds__(256) void k_biaspack(const float* __restrict__ bq,
                                                  const float* __restrict__ bk,
                                                  const float* __restrict__ bv,
                                                  float* __restrict__ dst) {
  int g = blockIdx.x * 256 + threadIdx.x;  // 9216
  int i = g / 3072, j = g - i * 3072;
  const float* src = (j < 1024)   ? bq + i * 1024 + j
                     : (j < 2048) ? bk + i * 1024 + (j - 1024)
                                  : bv + i * 1024 + (j - 2048);
  dst[g] = *src;
}

// ---------------------------------------------------------------------------
// Downsample x (fp32 [B,2048,1024]) -> bf16 scale-1/2/4 averaged copies
// ---------------------------------------------------------------------------
__global__ __launch_bounds__(256) void k_down(const float* __restrict__ x,
                                              uint16_t* __restrict__ x1,
                                              uint16_t* __restrict__ x2,
                                              uint16_t* __restrict__ x4) {
  int g = blockIdx.x * 256 + threadIdx.x;  // 2*512*1024 threads
  int c = g & 1023;
  int l4 = (g >> 10) & 511;
  int b = g >> 19;
  const float* xp = x + (size_t)(b * 2048 + l4 * 4) * 1024 + c;
  float a0 = xp[0], a1 = xp[1024], a2 = xp[2048], a3 = xp[3072];
  size_t r1 = (size_t)(b * 2048 + l4 * 4) * 1024 + c;
  x1[r1] = f2bf(a0);
  x1[r1 + 1024] = f2bf(a1);
  x1[r1 + 2048] = f2bf(a2);
  x1[r1 + 3072] = f2bf(a3);
  size_t r2 = (size_t)(b * 1024 + l4 * 2) * 1024 + c;
  x2[r2] = f2bf(0.5f * (a0 + a1));
  x2[r2 + 1024] = f2bf(0.5f * (a2 + a3));
  x4[(size_t)(b * 512 + l4) * 1024 + c] = f2bf(0.25f * (a0 + a1 + a2 + a3));
}

// ---------------------------------------------------------------------------
// bf16 GEMM, B^T input layout (BT[n][k]). v = acc*scale + bias; cols<qcols
// additionally multiplied by qscale (post-bias — used to pre-scale Q).
// qcols=0 reproduces the R4-proven path exactly.
// 128x128 tile, BK=32, 4 waves (2x2), 4x4 16x16x32 MFMA frags per wave.
// ---------------------------------------------------------------------------
__global__ __launch_bounds__(256) void k_gemm(
    const uint16_t* __restrict__ A, const uint16_t* __restrict__ BT,
    const float* __restrict__ bias, void* __restrict__ C, int M, int N, int K,
    int ldc, float scale, float qscale, int qcols, int out_bf16) {
  __shared__ __align__(16) uint16_t Al[128 * 32];
  __shared__ __align__(16) uint16_t Bl[128 * 32];
  const int tid = threadIdx.x;
  const int wave = tid >> 6, lane = tid & 63;
  const int wr = wave >> 1, wc = wave & 1;
  const int lr = lane & 15, lg = lane >> 4;
  const int bM = blockIdx.y * 128, bN = blockIdx.x * 128;
  (void)M; (void)N;

  f32x4 acc[4][4] = {};

  for (int k0 = 0; k0 < K; k0 += 32) {
    __syncthreads();  // previous tile's frag reads done before overwrite
#pragma unroll
    for (int j = 0; j < 2; ++j) {
      int ck = wave * 2 + j;          // 8 chunks of 1024B per tile
      int p = ck * 64 + lane;         // 16B chunk index
      int row = p >> 2, kq = p & 3;
      load_lds16(A + (size_t)(bM + row) * K + k0 + kq * 8, &Al[ck * 512]);
      load_lds16(BT + (size_t)(bN + row) * K + k0 + kq * 8, &Bl[ck * 512]);
    }
    __syncthreads();  // vmcnt(0) drain -> LDS ready
    s16x8 af[4], bfr[4];
#pragma unroll
    for (int i = 0; i < 4; ++i)
      af[i] = *(const s16x8*)&Al[(wr * 64 + i * 16 + lr) * 32 + lg * 8];
#pragma unroll
    for (int i = 0; i < 4; ++i)
      bfr[i] = *(const s16x8*)&Bl[(wc * 64 + i * 16 + lr) * 32 + lg * 8];
#pragma unroll
    for (int i = 0; i < 4; ++i)
#pragma unroll
      for (int jn = 0; jn < 4; ++jn)
        acc[i][jn] = __builtin_amdgcn_mfma_f32_16x16x32_bf16(
            af[i], bfr[jn], acc[i][jn], 0, 0, 0);
  }

  // epilogue: D layout col=lane&15, row=(lane>>4)*4+reg  [m89-verified]
#pragma unroll
  for (int i = 0; i < 4; ++i) {
    int rg = bM + wr * 64 + i * 16 + lg * 4;
#pragma unroll
    for (int jn = 0; jn < 4; ++jn) {
      int cg = bN + wc * 64 + jn * 16 + lr;
      float bv = bias ? bias[cg] : 0.f;
      float post = (cg < qcols) ? qscale : 1.f;
#pragma unroll
      for (int r = 0; r < 4; ++r) {
        float v = (acc[i][jn][r] * scale + bv) * post;
        if (out_bf16)
          ((uint16_t*)C)[(size_t)(rg + r) * ldc + cg] = f2bf(v);
        else
          ((float*)C)[(size_t)(rg + r) * ldc + cg] = v;
      }
    }
  }
}

// ---------------------------------------------------------------------------
// V transpose: v bf16 [B*S][ld] (col offset pre-applied) -> vt[(bh)*64+d][S]
// ---------------------------------------------------------------------------
__global__ __launch_bounds__(256) void k_vtrans(const uint16_t* __restrict__ v,
                                                uint16_t* __restrict__ vt,
                                                int S, int ld) {
  const int nKT = S >> 6;
  const int bh = blockIdx.x / nKT, kt = blockIdx.x % nKT;
  const int b = bh >> 4, h = bh & 15;
  __shared__ uint16_t t[64][65];
  for (int i = threadIdx.x; i < 4096; i += 256) {
    int kk = i >> 6, dd = i & 63;
    t[dd][kk] = v[(size_t)(b * S + kt * 64 + kk) * ld + h * 64 + dd];
  }
  __syncthreads();
  for (int i = threadIdx.x; i < 4096; i += 256) {
    int dd = i >> 6, kk = i & 63;
    vt[((size_t)(bh * 64) + dd) * S + kt * 64 + kk] = t[dd][kk];
  }
}

// ---------------------------------------------------------------------------
// Flash attention. qkv: [B*S][3072] packed, Q cols pre-scaled by
// 0.125*log2(e) so scores are already in the exp2 domain.
// vt: [(b*16+h)*64+d][S]. One wave per (b,h, 32-q-row block): 2 16-row frags.
// S^T = mfma(K,Q): lane holds 4 k-scores of q=lane&15 (k=(lane>>4)*4+r).
// Exact defer-rescale: skip acc/lS rescale when no lane's max grew.
// V frags shared across frags; K/V register double-buffered one tile ahead.
// ---------------------------------------------------------------------------
__global__ __launch_bounds__(256) void k_attn(const uint16_t* __restrict__ qkv,
                                              const uint16_t* __restrict__ vt,
                                              uint16_t* __restrict__ ctx,
                                              int S) {
  const int wid = blockIdx.x * 4 + (threadIdx.x >> 6);
  const int lane = threadIdx.x & 63;
  const int nQB = S >> 5;
  const int qb = wid % nQB;
  const int bh = wid / nQB;  // b*16+h
  const int h = bh & 15, b = bh >> 4;
  const int lr = lane & 15, lg = lane >> 4;

  const uint16_t* qp =
      qkv + (size_t)(b * S + qb * 32 + lr) * 3072 + h * 64 + lg * 8;
  s16x8 qf0[2], qf1[2];
  qf0[0] = *(const s16x8*)qp;
  qf1[0] = *(const s16x8*)(qp + 32);
  qf0[1] = *(const s16x8*)(qp + 16 * 3072);
  qf1[1] = *(const s16x8*)(qp + 16 * 3072 + 32);
  const uint16_t* kbase =
      qkv + (size_t)(b * S) * 3072 + 1024 + h * 64 + lg * 8;
  const uint16_t* vbase = vt + (size_t)(bh * 64) * S + lg * 4;

  f32x4 acc[2][4] = {};
  float mS[2] = {-1e30f, -1e30f};
  float lS[2] = {0.f, 0.f};

#define LOADK(T, K0, K1)                                               \
  {                                                                    \
    const uint16_t* kp = kbase + (size_t)((T)*16 + lr) * 3072;         \
    K0 = *(const s16x8*)kp;                                            \
    K1 = *(const s16x8*)(kp + 32);                                     \
  }
#define LOADV(T, VF)                                                   \
  {                                                                    \
    _Pragma("unroll") for (int c = 0; c < 4; ++c) VF[c] =              \
        *(const s16x4*)(vbase + (size_t)(c * 16 + lr) * S + (T)*16);   \
  }

  auto compute = [&](s16x8 K0, s16x8 K1, const s16x4 (&VF)[4]) {
#pragma unroll
    for (int f = 0; f < 2; ++f) {
      f32x4 st = {};
      st = __builtin_amdgcn_mfma_f32_16x16x32_bf16(K0, qf0[f], st, 0, 0, 0);
      st = __builtin_amdgcn_mfma_f32_16x16x32_bf16(K1, qf1[f], st, 0, 0, 0);
      // st is already scaled: (q.k)/8 * log2(e)  -> exp2 domain
      float tmax = fmaxf(fmaxf(st[0], st[1]), fmaxf(st[2], st[3]));
      tmax = fmaxf(tmax, __shfl_xor(tmax, 16));
      tmax = fmaxf(tmax, __shfl_xor(tmax, 32));
      if (!__all(tmax <= mS[f])) {
        // some lane's max grew: standard rescale. Lanes with tmax<=mS get
        // fac = exp2(0) = 1.0 exactly -> bit-identical to unconditional path.
        float mn = fmaxf(mS[f], tmax);
        float fac = fexp2(mS[f] - mn);
        mS[f] = mn;
        lS[f] *= fac;
#pragma unroll
        for (int c = 0; c < 4; ++c) acc[f][c] *= fac;
      }
      float p0 = fexp2(st[0] - mS[f]), p1 = fexp2(st[1] - mS[f]);
      float p2 = fexp2(st[2] - mS[f]), p3 = fexp2(st[3] - mS[f]);
      lS[f] += (p0 + p1) + (p2 + p3);
      s16x4 pb;
      pb[0] = (short)f2bf(p0);
      pb[1] = (short)f2bf(p1);
      pb[2] = (short)f2bf(p2);
      pb[3] = (short)f2bf(p3);
#pragma unroll
      for (int c = 0; c < 4; ++c)
        acc[f][c] = __builtin_amdgcn_mfma_f32_16x16x16bf16_1k(VF[c], pb,
                                                              acc[f][c], 0, 0, 0);
    }
  };

  s16x8 ka0, ka1, kb0, kb1;
  s16x4 va[4], vb[4];
  const int nT = S >> 4;  // even
  LOADK(0, ka0, ka1);
  LOADV(0, va);
  LOADK(1, kb0, kb1);
  LOADV(1, vb);
  for (int t = 0; t < nT; t += 2) {
    compute(ka0, ka1, va);
    if (t + 2 < nT) { LOADK(t + 2, ka0, ka1); LOADV(t + 2, va); }
    compute(kb0, kb1, vb);
    if (t + 3 < nT) { LOADK(t + 3, kb0, kb1); LOADV(t + 3, vb); }
  }
#undef LOADK
#undef LOADV

#pragma unroll
  for (int f = 0; f < 2; ++f) {
    float l = lS[f];
    l += __shfl_xor(l, 16);
    l += __shfl_xor(l, 32);
    const float inv = 1.f / l;
    uint16_t* crow =
        ctx + (size_t)(b * S + qb * 32 + f * 16 + lr) * 1024 + h * 64;
#pragma unroll
    for (int c = 0; c < 4; ++c) {
      u16x4 o;
#pragma unroll
      for (int r = 0; r < 4; ++r) o[r] = f2bf(acc[f][c][r] * inv);
      *(u16x4*)(crow + c * 16 + lg * 4) = o;
    }
  }
}

// ---------------------------------------------------------------------------
// Row softmax over M=1024: sim fp32 [4096][1024] -> weights bf16
// ---------------------------------------------------------------------------
__global__ __launch_bounds__(256) void k_softmax(const float* __restrict__ sim,
                                                 uint16_t* __restrict__ w) {
  __shared__ float red[4];
  const int row = blockIdx.x, t = threadIdx.x;
  const size_t base = (size_t)row * 1024 + t * 4;
  float4 v = *(const float4*)(sim + base);
  float mx = fmaxf(fmaxf(v.x, v.y), fmaxf(v.z, v.w));
#pragma unroll
  for (int o = 32; o > 0; o >>= 1) mx = fmaxf(mx, __shfl_xor(mx, o));
  if ((t & 63) == 0) red[t >> 6] = mx;
  __syncthreads();
  mx = fmaxf(fmaxf(red[0], red[1]), fmaxf(red[2], red[3]));
  __syncthreads();
  float p0 = __expf(v.x - mx), p1 = __expf(v.y - mx);
  float p2 = __expf(v.z - mx), p3 = __expf(v.w - mx);
  float s = p0 + p1 + p2 + p3;
#pragma unroll
  for (int o = 32; o > 0; o >>= 1) s += __shfl_xor(s, o);
  if ((t & 63) == 0) red[t >> 6] = s;
  __syncthreads();
  s = red[0] + red[1] + red[2] + red[3];
  float inv = 1.f / s;
  u16x4 o = {f2bf(p0 * inv), f2bf(p1 * inv), f2bf(p2 * inv), f2bf(p3 * inv)};
  *(u16x4*)(w + base) = o;
}

// ---------------------------------------------------------------------------
// Upsample scores2/scores4 into Acf columns 1024..3071 (bf16)
// ---------------------------------------------------------------------------
__global__ __launch_bounds__(256) void k_upsample(const uint16_t* __restrict__ s2,
                                                  const uint16_t* __restrict__ s4,
                                                  uint16_t* __restrict__ acf) {
  int g = blockIdx.x * 256 + threadIdx.x;  // 4096 rows * 256 groups
  int cg = g & 255;
  int row = g >> 8;
  int b = row >> 11, l = row & 2047;
  int c = cg * 8;
  const uint16_t* src =
      (c < 1024) ? s2 + (size_t)(b * 1024 + (l >> 1)) * 1024 + c
                 : s4 + (size_t)(b * 512 + (l >> 2)) * 1024 + (c - 1024);
  *(s16x8*)(acf + (size_t)row * 4096 + 1024 + c) = *(const s16x8*)src;
}

// ---------------------------------------------------------------------------
// Final: LayerNorm(cf)+ReLU, gate=sigmoid(gl), confidence, residual.
// ---------------------------------------------------------------------------
__global__ __launch_bounds__(256) void k_final(
    const float* __restrict__ cf, const float* __restrict__ gl,
    const float* __restrict__ x, const float* __restrict__ lns,
    const float* __restrict__ lnb, float* __restrict__ out) {
  __shared__ float red[4];
  const int row = blockIdx.x, t = threadIdx.x;
  const size_t base = (size_t)row * 1024 + t * 4;
  float4 cv = *(const float4*)(cf + base);
  float4 gv = *(const float4*)(gl + base);
  float g0 = 1.f / (1.f + __expf(-gv.x));
  float g1 = 1.f / (1.f + __expf(-gv.y));
  float g2 = 1.f / (1.f + __expf(-gv.z));
  float g3 = 1.f / (1.f + __expf(-gv.w));

  auto bsum = [&](float v) -> float {
#pragma unroll
    for (int o = 32; o > 0; o >>= 1) v += __shfl_xor(v, o);
    if ((t & 63) == 0) red[t >> 6] = v;
    __syncthreads();
    float r = red[0] + red[1] + red[2] + red[3];
    __syncthreads();
    return r;
  };
  float mu = bsum(cv.x + cv.y + cv.z + cv.w) * (1.f / 1024.f);
  float conf = bsum(g0 + g1 + g2 + g3) * (1.f / 1024.f);
  float d0 = cv.x - mu, d1 = cv.y - mu, d2 = cv.z - mu, d3 = cv.w - mu;
  float var = bsum(d0 * d0 + d1 * d1 + d2 * d2 + d3 * d3) * (1.f / 1024.f);
  float rstd = rsqrtf(var + 1e-6f);
  float4 ls = *(const float4*)(lns + t * 4);
  float4 lb = *(const float4*)(lnb + t * 4);
  float y0 = fmaxf(d0 * rstd * ls.x + lb.x, 0.f);
  float y1 = fmaxf(d1 * rstd * ls.y + lb.y, 0.f);
  float y2 = fmaxf(d2 * rstd * ls.z + lb.z, 0.f);
  float y3 = fmaxf(d3 * rstd * ls.w + lb.w, 0.f);
  float sc = sqrtf(1.f / (1024.f * conf + 1e-6f));
  float4 xv = *(const float4*)(x + base);
  float4 o1 = {xv.x + sc * g0 * y0, xv.y + sc * g1 * y1, xv.z + sc * g2 * y2,
               xv.w + sc * g3 * y3};
  *(float4*)(out + base) = o1;
  float4 o2 = {g0, g1, g2, g3};
  *(float4*)(out + 4194304 + base) = o2;
}

// ---------------------------------------------------------------------------
// Workspace layout (bytes)
// ---------------------------------------------------------------------------
static constexpr size_t OFF_QKVT = 0;            // 3 scales x 6 MiB (Wq|Wk|Wv)^T
static constexpr size_t OFF_WOT = 18 * MiBc;     // 3 x 2 MiB
static constexpr size_t OFF_W1T = 24 * MiBc;     // 8
static constexpr size_t OFF_W2T = 32 * MiBc;     // 2
static constexpr size_t OFF_EMB = 34 * MiBc;     // 2
static constexpr size_t OFF_EMT = 36 * MiBc;     // 2
static constexpr size_t OFF_XB1 = 38 * MiBc;     // 8
static constexpr size_t OFF_XB2 = 46 * MiBc;     // 4
static constexpr size_t OFF_XB4 = 50 * MiBc;     // 2
static constexpr size_t OFF_QKV = 52 * MiBc;     // 24 (reused per scale)
static constexpr size_t OFF_VT  = 76 * MiBc;     // 8
static constexpr size_t OFF_CTX = 84 * MiBc;     // 8
static constexpr size_t OFF_S2  = 92 * MiBc;     // 4
static constexpr size_t OFF_S4  = 96 * MiBc;     // 2
static constexpr size_t OFF_ACF = 98 * MiBc;     // 32
static constexpr size_t OFF_SIM = 130 * MiBc;    // 16 (fp32)
static constexpr size_t OFF_WSM = 146 * MiBc;    // 8
static constexpr size_t OFF_CF  = 154 * MiBc;    // 16 (fp32)
static constexpr size_t OFF_BQKV = 170 * MiBc;   // 36 KB (gate logits in d_out)
static constexpr size_t WS_NEED = 186 * MiBc;

static constexpr float QSC = 0.125f * 1.44269504f;  // 1/sqrt(64) * log2(e)

extern "C" void kernel_launch(void* const* d_in, const int* in_sizes, int n_in,
                              void* d_out, int out_size, void* d_ws,
                              size_t ws_size, hipStream_t stream) {
  (void)in_sizes; (void)n_in; (void)out_size;
  const float* x  = (const float*)d_in[0];
  const float* em = (const float*)d_in[1];
  const float* Wq = (const float*)d_in[2];
  const float* bq = (const float*)d_in[3];
  const float* Wk = (const float*)d_in[4];
  const float* bk = (const float*)d_in[5];
  const float* Wv = (const float*)d_in[6];
  const float* bv = (const float*)d_in[7];
  const float* Wo = (const float*)d_in[8];
  const float* bo = (const float*)d_in[9];
  const float* W1 = (const float*)d_in[10];
  const float* b1 = (const float*)d_in[11];
  const float* lns = (const float*)d_in[12];
  const float* lnb = (const float*)d_in[13];
  const float* W2 = (const float*)d_in[14];
  const float* b2 = (const float*)d_in[15];
  float* out = (float*)d_out;

  if (ws_size < WS_NEED) {  // sentinel: makes ws-too-small distinguishable
    hipMemsetAsync(d_out, 0x7f, 4, stream);
    return;
  }
  uint8_t* w8 = (uint8_t*)d_ws;
  auto U16 = [&](size_t off) { return (uint16_t*)(w8 + off); };
  uint16_t* QKVT = U16(OFF_QKVT);
  uint16_t* WOT = U16(OFF_WOT);
  uint16_t* W1T = U16(OFF_W1T);
  uint16_t* W2T = U16(OFF_W2T);
  uint16_t* EMB = U16(OFF_EMB);
  uint16_t* EMT = U16(OFF_EMT);
  uint16_t* XB1 = U16(OFF_XB1);
  uint16_t* XB2 = U16(OFF_XB2);
  uint16_t* XB4 = U16(OFF_XB4);
  uint16_t* QKVb = U16(OFF_QKV);
  uint16_t* VTb = U16(OFF_VT);
  uint16_t* CTX = U16(OFF_CTX);
  uint16_t* S2b = U16(OFF_S2);
  uint16_t* S4b = U16(OFF_S4);
  uint16_t* ACF = U16(OFF_ACF);
  float* SIM = (float*)(w8 + OFF_SIM);
  uint16_t* WSM = U16(OFF_WSM);
  float* CF = (float*)(w8 + OFF_CF);
  float* BQKV = (float*)(w8 + OFF_BQKV);
  float* GL = out + 4194304;  // gate logits in-place in d_out gate region

  const size_t MM = 1024 * 1024;
  const size_t SC3 = 3 * MM;  // elements per packed QKV^T scale

  // 1) weight prep: transposes to B^T layout (QKV packed), EM bf16, biases
  TD14 td{};
  for (int i = 0; i < 3; ++i) {
    td.d[i]     = {Wq + (size_t)i * MM, QKVT + (size_t)i * SC3};
    td.d[3 + i] = {Wk + (size_t)i * MM, QKVT + (size_t)i * SC3 + MM};
    td.d[6 + i] = {Wv + (size_t)i * MM, QKVT + (size_t)i * SC3 + 2 * MM};
    td.d[9 + i] = {Wo + (size_t)i * MM, WOT + (size_t)i * MM};
  }
  td.d[12] = {W2, W2T};
  td.d[13] = {em, EMT};
  k_transpose<<<dim3(1024, 14), 256, 0, stream>>>(td, 1024, 1024);
  TD14 t1{};
  t1.d[0] = {W1, W1T};
  k_transpose<<<dim3(4096, 1), 256, 0, stream>>>(t1, 4096, 1024);
  k_f2bf4<<<dim3(1024), 256, 0, stream>>>(em, EMB);
  k_biaspack<<<dim3(36), 256, 0, stream>>>(bq, bk, bv, BQKV);
  k_down<<<dim3(4096), 256, 0, stream>>>(x, XB1, XB2, XB4);

  // 2) per-scale self-attention (merged QKV GEMM, N=3072; Q cols post-scaled
  //    by QSC so attention scores land directly in the exp2 domain)
  for (int i = 0; i < 3; ++i) {
    const int S = 2048 >> i;
    const int R = 2 * S;
    const uint16_t* xb = (i == 0) ? XB1 : (i == 1) ? XB2 : XB4;
    k_gemm<<<dim3(24, R / 128), 256, 0, stream>>>(
        xb, QKVT + (size_t)i * SC3, BQKV + i * 3072, QKVb, R, 3072, 1024, 3072,
        1.f, QSC, 1024, 1);
    k_vtrans<<<dim3(32 * (S / 64)), 256, 0, stream>>>(QKVb + 2048, VTb, S, 3072);
    k_attn<<<dim3(S / 4), 256, 0, stream>>>(QKVb, VTb, CTX, S);
    dim3 gg(8, R / 128);
    if (i == 0)
      k_gemm<<<gg, 256, 0, stream>>>(CTX, WOT, bo, ACF, R, 1024, 1024, 4096,
                                     1.f, 1.f, 0, 1);
    else if (i == 1)
      k_gemm<<<gg, 256, 0, stream>>>(CTX, WOT + MM, bo + 1024, S2b, R, 1024,
                                     1024, 1024, 1.f, 1.f, 0, 1);
    else
      k_gemm<<<gg, 256, 0, stream>>>(CTX, WOT + 2 * MM, bo + 2048, S4b, R, 1024,
                                     1024, 1024, 1.f, 1.f, 0, 1);
  }

  // 3) memory path: sim -> softmax -> readback (into Acf cols 3072..4095)
  k_gemm<<<dim3(8, 32), 256, 0, stream>>>(XB1, EMB, nullptr, SIM, 4096, 1024,
                                          1024, 1024, 0.03125f, 1.f, 0, 0);
  k_softmax<<<dim3(4096), 256, 0, stream>>>(SIM, WSM);
  k_gemm<<<dim3(8, 32), 256, 0, stream>>>(WSM, EMT, nullptr, ACF + 3072, 4096,
                                          1024, 1024, 4096, 1.f, 1.f, 0, 1);
  k_upsample<<<dim3(4096), 256, 0, stream>>>(S2b, S4b, ACF);

  // 4) cf GEMM (K=4096), gate GEMM, fused LN/gate/residual
  k_gemm<<<dim3(8, 32), 256, 0, stream>>>(ACF, W1T, b1, CF, 4096, 1024, 4096,
                                          1024, 1.f, 1.f, 0, 0);
  k_gemm<<<dim3(8, 32), 256, 0, stream>>>(XB1, W2T, b2, GL, 4096, 1024, 1024,
                                          1024, 1.f, 1.f, 0, 0);
  k_final<<<dim3(4096), 256, 0, stream>>>(CF, GL, x, lns, lnb, out);
}

// Round 8
// 808.707 us; speedup vs baseline: 1.0117x; 1.0117x over previous
//
#include <hip/hip_runtime.h>
#include <stdint.h>

// ---------------------------------------------------------------------------
// ErrorCorrectionModule on MI355X (gfx950)
// B=2, L=2048, H=1024, NH=16, HD=64, M=1024, SCALES=(1,2,4)
// R7: attn in-block split-K. Block = 4 waves on the SAME (bh, 32 q-rows);
// wave w processes k-tiles w, w+4, w+8... (stride 4, reg double-buffered
// stride 8). End: exact flash-merge of the 4 partials (m, l, acc) via LDS
// (18 KB). 4x wave count fixes the 22%-occupancy latency bound seen in R6.
// Softmax numerics unchanged from R6 (exp2 domain, exact defer-rescale).
// ---------------------------------------------------------------------------

#define MiBc ((size_t)1 << 20)

using s16x8 = __attribute__((ext_vector_type(8))) short;   // 8 bf16 (4 VGPR)
using s16x4 = __attribute__((ext_vector_type(4))) short;   // 4 bf16 (2 VGPR)
using u16x4 = __attribute__((ext_vector_type(4))) unsigned short;
using f32x4 = __attribute__((ext_vector_type(4))) float;

__device__ __forceinline__ uint16_t f2bf(float f) {
  uint32_t u = __float_as_uint(f);
  return (uint16_t)((u + 0x7fffu + ((u >> 16) & 1u)) >> 16);  // RNE
}

__device__ __forceinline__ float fexp2(float x) {
  return __builtin_amdgcn_exp2f(x);  // raw v_exp_f32 (2^x)
}

// async global->LDS, 16B per lane; LDS dest is wave-uniform base + lane*16
__device__ __forceinline__ void load_lds16(const uint16_t* g, uint16_t* l) {
  __builtin_amdgcn_global_load_lds(
      (const __attribute__((address_space(1))) void*)(const void*)g,
      (__attribute__((address_space(3))) void*)(void*)l, 16, 0, 0);
}

// ---------------------------------------------------------------------------
// Transpose fp32 [R][C] -> bf16 [C][R]  (B^T weight layout builder)
// ---------------------------------------------------------------------------
struct TD { const float* in; uint16_t* out; };
struct TD14 { TD d[14]; };

__global__ __launch_bounds__(256) void k_transpose(TD14 ds, int R, int C) {
  const float* in = ds.d[blockIdx.y].in;
  uint16_t* out = ds.d[blockIdx.y].out;
  const int nTC = C >> 5;
  const int bi = blockIdx.x / nTC, bj = blockIdx.x % nTC;
  __shared__ float t[32][33];
  const int tx = threadIdx.x & 31, ty = threadIdx.x >> 5;  // ty 0..7
#pragma unroll
  for (int p = 0; p < 4; ++p) {
    int r = bi * 32 + ty + p * 8;
    t[ty + p * 8][tx] = in[(size_t)r * C + bj * 32 + tx];
  }
  __syncthreads();
#pragma unroll
  for (int p = 0; p < 4; ++p) {
    int c = bj * 32 + ty + p * 8;
    out[(size_t)c * R + bi * 32 + tx] = f2bf(t[tx][ty + p * 8]);
  }
}

// plain fp32 -> bf16 convert (error_memory, kept row-major for sim's B^T)
__global__ __launch_bounds__(256) void k_f2bf4(const float* __restrict__ in,
                                               uint16_t* __restrict__ out) {
  int i = (blockIdx.x * 256 + threadIdx.x) * 4;
  float4 v = *(const float4*)(in + i);
  u16x4 o = {f2bf(v.x), f2bf(v.y), f2bf(v.z), f2bf(v.w)};
  *(u16x4*)(out + i) = o;
}

// pack bq|bk|bv (3 scales) into BQKV[3][3072]
__global__ __launch_bounds__(256) void k_biaspack(const float* __restrict__ bq,
                                                  const float* __restrict__ bk,
                                                  const float* __restrict__ bv,
                                                  float* __restrict__ dst) {
  int g = blockIdx.x * 256 + threadIdx.x;  // 9216
  int i = g / 3072, j = g - i * 3072;
  const float* src = (j < 1024)   ? bq + i * 1024 + j
                     : (j < 2048) ? bk + i * 1024 + (j - 1024)
                                  : bv + i * 1024 + (j - 2048);
  dst[g] = *src;
}

// ---------------------------------------------------------------------------
// Downsample x (fp32 [B,2048,1024]) -> bf16 scale-1/2/4 averaged copies
// ---------------------------------------------------------------------------
__global__ __launch_bounds__(256) void k_down(const float* __restrict__ x,
                                              uint16_t* __restrict__ x1,
                                              uint16_t* __restrict__ x2,
                                              uint16_t* __restrict__ x4) {
  int g = blockIdx.x * 256 + threadIdx.x;  // 2*512*1024 threads
  int c = g & 1023;
  int l4 = (g >> 10) & 511;
  int b = g >> 19;
  const float* xp = x + (size_t)(b * 2048 + l4 * 4) * 1024 + c;
  float a0 = xp[0], a1 = xp[1024], a2 = xp[2048], a3 = xp[3072];
  size_t r1 = (size_t)(b * 2048 + l4 * 4) * 1024 + c;
  x1[r1] = f2bf(a0);
  x1[r1 + 1024] = f2bf(a1);
  x1[r1 + 2048] = f2bf(a2);
  x1[r1 + 3072] = f2bf(a3);
  size_t r2 = (size_t)(b * 1024 + l4 * 2) * 1024 + c;
  x2[r2] = f2bf(0.5f * (a0 + a1));
  x2[r2 + 1024] = f2bf(0.5f * (a2 + a3));
  x4[(size_t)(b * 512 + l4) * 1024 + c] = f2bf(0.25f * (a0 + a1 + a2 + a3));
}

// ---------------------------------------------------------------------------
// bf16 GEMM, B^T input layout (BT[n][k]). v = (acc*scale + bias) * post,
// post = qscale for cols < qcols else 1 (used to pre-scale Q into exp2 dom).
// 128x128 tile, BK=32, 4 waves (2x2), 4x4 16x16x32 MFMA frags per wave.
// ---------------------------------------------------------------------------
__global__ __launch_bounds__(256) void k_gemm(
    const uint16_t* __restrict__ A, const uint16_t* __restrict__ BT,
    const float* __restrict__ bias, void* __restrict__ C, int M, int N, int K,
    int ldc, float scale, float qscale, int qcols, int out_bf16) {
  __shared__ __align__(16) uint16_t Al[128 * 32];
  __shared__ __align__(16) uint16_t Bl[128 * 32];
  const int tid = threadIdx.x;
  const int wave = tid >> 6, lane = tid & 63;
  const int wr = wave >> 1, wc = wave & 1;
  const int lr = lane & 15, lg = lane >> 4;
  const int bM = blockIdx.y * 128, bN = blockIdx.x * 128;
  (void)M; (void)N;

  f32x4 acc[4][4] = {};

  for (int k0 = 0; k0 < K; k0 += 32) {
    __syncthreads();  // previous tile's frag reads done before overwrite
#pragma unroll
    for (int j = 0; j < 2; ++j) {
      int ck = wave * 2 + j;          // 8 chunks of 1024B per tile
      int p = ck * 64 + lane;         // 16B chunk index
      int row = p >> 2, kq = p & 3;
      load_lds16(A + (size_t)(bM + row) * K + k0 + kq * 8, &Al[ck * 512]);
      load_lds16(BT + (size_t)(bN + row) * K + k0 + kq * 8, &Bl[ck * 512]);
    }
    __syncthreads();  // vmcnt(0) drain -> LDS ready
    s16x8 af[4], bfr[4];
#pragma unroll
    for (int i = 0; i < 4; ++i)
      af[i] = *(const s16x8*)&Al[(wr * 64 + i * 16 + lr) * 32 + lg * 8];
#pragma unroll
    for (int i = 0; i < 4; ++i)
      bfr[i] = *(const s16x8*)&Bl[(wc * 64 + i * 16 + lr) * 32 + lg * 8];
#pragma unroll
    for (int i = 0; i < 4; ++i)
#pragma unroll
      for (int jn = 0; jn < 4; ++jn)
        acc[i][jn] = __builtin_amdgcn_mfma_f32_16x16x32_bf16(
            af[i], bfr[jn], acc[i][jn], 0, 0, 0);
  }

  // epilogue: D layout col=lane&15, row=(lane>>4)*4+reg  [m89-verified]
#pragma unroll
  for (int i = 0; i < 4; ++i) {
    int rg = bM + wr * 64 + i * 16 + lg * 4;
#pragma unroll
    for (int jn = 0; jn < 4; ++jn) {
      int cg = bN + wc * 64 + jn * 16 + lr;
      float bv = bias ? bias[cg] : 0.f;
      float post = (cg < qcols) ? qscale : 1.f;
#pragma unroll
      for (int r = 0; r < 4; ++r) {
        float v = (acc[i][jn][r] * scale + bv) * post;
        if (out_bf16)
          ((uint16_t*)C)[(size_t)(rg + r) * ldc + cg] = f2bf(v);
        else
          ((float*)C)[(size_t)(rg + r) * ldc + cg] = v;
      }
    }
  }
}

// ---------------------------------------------------------------------------
// V transpose: v bf16 [B*S][ld] (col offset pre-applied) -> vt[(bh)*64+d][S]
// ---------------------------------------------------------------------------
__global__ __launch_bounds__(256) void k_vtrans(const uint16_t* __restrict__ v,
                                                uint16_t* __restrict__ vt,
                                                int S, int ld) {
  const int nKT = S >> 6;
  const int bh = blockIdx.x / nKT, kt = blockIdx.x % nKT;
  const int b = bh >> 4, h = bh & 15;
  __shared__ uint16_t t[64][65];
  for (int i = threadIdx.x; i < 4096; i += 256) {
    int kk = i >> 6, dd = i & 63;
    t[dd][kk] = v[(size_t)(b * S + kt * 64 + kk) * ld + h * 64 + dd];
  }
  __syncthreads();
  for (int i = threadIdx.x; i < 4096; i += 256) {
    int dd = i >> 6, kk = i & 63;
    vt[((size_t)(bh * 64) + dd) * S + kt * 64 + kk] = t[dd][kk];
  }
}

// ---------------------------------------------------------------------------
// Flash attention, in-block split-K. qkv: [B*S][3072] (Q cols pre-scaled by
// 0.125*log2e -> exp2 domain), vt: [(b*16+h)*64+d][S].
// Block (256T) = one (bh, 32-q-row) unit; wave w handles k-tiles w, w+4, ...
// Each wave: S^T = mfma(K,Q), lane-local online softmax (exact defer-rescale),
// PV^T accumulate. End: exact flash-merge of 4 partials via LDS; wave w
// stores output quarter c=w.
// ---------------------------------------------------------------------------
__global__ __launch_bounds__(256) void k_attn(const uint16_t* __restrict__ qkv,
                                              const uint16_t* __restrict__ vt,
                                              uint16_t* __restrict__ ctx,
                                              int S) {
  __shared__ float2 mlb[4][64];                      // 2 KB
  __shared__ __align__(16) float accb[4][64][4][4];  // 16 KB
  const int lane = threadIdx.x & 63;
  const int wv = threadIdx.x >> 6;
  const int nQB = S >> 5;
  const int bh = blockIdx.x / nQB;  // b*16+h
  const int qb = blockIdx.x % nQB;
  const int h = bh & 15, b = bh >> 4;
  const int lr = lane & 15, lg = lane >> 4;

  const uint16_t* qp =
      qkv + (size_t)(b * S + qb * 32 + lr) * 3072 + h * 64 + lg * 8;
  s16x8 qf0[2], qf1[2];
  qf0[0] = *(const s16x8*)qp;
  qf1[0] = *(const s16x8*)(qp + 32);
  qf0[1] = *(const s16x8*)(qp + 16 * 3072);
  qf1[1] = *(const s16x8*)(qp + 16 * 3072 + 32);
  const uint16_t* kbase =
      qkv + (size_t)(b * S) * 3072 + 1024 + h * 64 + lg * 8;
  const uint16_t* vbase = vt + (size_t)(bh * 64) * S + lg * 4;

  f32x4 acc[2][4] = {};
  float mS[2] = {-1e30f, -1e30f};
  float lS[2] = {0.f, 0.f};

#define LOADK(T, K0, K1)                                               \
  {                                                                    \
    const uint16_t* kp = kbase + (size_t)((T)*16 + lr) * 3072;         \
    K0 = *(const s16x8*)kp;                                            \
    K1 = *(const s16x8*)(kp + 32);                                     \
  }
#define LOADV(T, VF)                                                   \
  {                                                                    \
    _Pragma("unroll") for (int c = 0; c < 4; ++c) VF[c] =              \
        *(const s16x4*)(vbase + (size_t)(c * 16 + lr) * S + (T)*16);   \
  }

  auto compute = [&](s16x8 K0, s16x8 K1, const s16x4 (&VF)[4]) {
#pragma unroll
    for (int f = 0; f < 2; ++f) {
      f32x4 st = {};
      st = __builtin_amdgcn_mfma_f32_16x16x32_bf16(K0, qf0[f], st, 0, 0, 0);
      st = __builtin_amdgcn_mfma_f32_16x16x32_bf16(K1, qf1[f], st, 0, 0, 0);
      float tmax = fmaxf(fmaxf(st[0], st[1]), fmaxf(st[2], st[3]));
      tmax = fmaxf(tmax, __shfl_xor(tmax, 16));
      tmax = fmaxf(tmax, __shfl_xor(tmax, 32));
      if (!__all(tmax <= mS[f])) {
        float mn = fmaxf(mS[f], tmax);
        float fac = fexp2(mS[f] - mn);
        mS[f] = mn;
        lS[f] *= fac;
#pragma unroll
        for (int c = 0; c < 4; ++c) acc[f][c] *= fac;
      }
      float p0 = fexp2(st[0] - mS[f]), p1 = fexp2(st[1] - mS[f]);
      float p2 = fexp2(st[2] - mS[f]), p3 = fexp2(st[3] - mS[f]);
      lS[f] += (p0 + p1) + (p2 + p3);
      s16x4 pb;
      pb[0] = (short)f2bf(p0);
      pb[1] = (short)f2bf(p1);
      pb[2] = (short)f2bf(p2);
      pb[3] = (short)f2bf(p3);
#pragma unroll
      for (int c = 0; c < 4; ++c)
        acc[f][c] = __builtin_amdgcn_mfma_f32_16x16x16bf16_1k(VF[c], pb,
                                                              acc[f][c], 0, 0, 0);
    }
  };

  // k-tiles for this wave: wv, wv+4, wv+8, ...  (nT >= 32, nT/4 even)
  s16x8 ka0, ka1, kb0, kb1;
  s16x4 va[4], vb[4];
  const int nT = S >> 4;
  LOADK(wv, ka0, ka1);
  LOADV(wv, va);
  LOADK(wv + 4, kb0, kb1);
  LOADV(wv + 4, vb);
  for (int t = wv; t < nT; t += 8) {
    compute(ka0, ka1, va);
    if (t + 8 < nT) { LOADK(t + 8, ka0, ka1); LOADV(t + 8, va); }
    compute(kb0, kb1, vb);
    if (t + 12 < nT) { LOADK(t + 12, kb0, kb1); LOADV(t + 12, vb); }
  }
#undef LOADK
#undef LOADV

  // exact flash-merge of the 4 wave partials, one f-round at a time.
#pragma unroll
  for (int f = 0; f < 2; ++f) {
    float lred = lS[f];
    lred += __shfl_xor(lred, 16);
    lred += __shfl_xor(lred, 32);
    mlb[wv][lane] = {mS[f], lred};
#pragma unroll
    for (int c = 0; c < 4; ++c)
      *(f32x4*)&accb[wv][lane][c][0] = acc[f][c];
    __syncthreads();  // partials visible to all waves
    float2 ml0 = mlb[0][lane], ml1 = mlb[1][lane];
    float2 ml2 = mlb[2][lane], ml3 = mlb[3][lane];
    float M = fmaxf(fmaxf(ml0.x, ml1.x), fmaxf(ml2.x, ml3.x));
    float s0 = fexp2(ml0.x - M), s1 = fexp2(ml1.x - M);
    float s2 = fexp2(ml2.x - M), s3 = fexp2(ml3.x - M);
    float L = s0 * ml0.y + s1 * ml1.y + s2 * ml2.y + s3 * ml3.y;
    f32x4 O = *(const f32x4*)&accb[0][lane][wv][0] * s0;
    O += *(const f32x4*)&accb[1][lane][wv][0] * s1;
    O += *(const f32x4*)&accb[2][lane][wv][0] * s2;
    O += *(const f32x4*)&accb[3][lane][wv][0] * s3;
    const float inv = 1.f / L;
    uint16_t* crow =
        ctx + (size_t)(b * S + qb * 32 + f * 16 + lr) * 1024 + h * 64;
    u16x4 o;
#pragma unroll
    for (int r = 0; r < 4; ++r) o[r] = f2bf(O[r] * inv);
    *(u16x4*)(crow + wv * 16 + lg * 4) = o;
    __syncthreads();  // protect LDS reuse for next f-round
  }
}

// ---------------------------------------------------------------------------
// Row softmax over M=1024: sim fp32 [4096][1024] -> weights bf16
// ---------------------------------------------------------------------------
__global__ __launch_bounds__(256) void k_softmax(const float* __restrict__ sim,
                                                 uint16_t* __restrict__ w) {
  __shared__ float red[4];
  const int row = blockIdx.x, t = threadIdx.x;
  const size_t base = (size_t)row * 1024 + t * 4;
  float4 v = *(const float4*)(sim + base);
  float mx = fmaxf(fmaxf(v.x, v.y), fmaxf(v.z, v.w));
#pragma unroll
  for (int o = 32; o > 0; o >>= 1) mx = fmaxf(mx, __shfl_xor(mx, o));
  if ((t & 63) == 0) red[t >> 6] = mx;
  __syncthreads();
  mx = fmaxf(fmaxf(red[0], red[1]), fmaxf(red[2], red[3]));
  __syncthreads();
  float p0 = __expf(v.x - mx), p1 = __expf(v.y - mx);
  float p2 = __expf(v.z - mx), p3 = __expf(v.w - mx);
  float s = p0 + p1 + p2 + p3;
#pragma unroll
  for (int o = 32; o > 0; o >>= 1) s += __shfl_xor(s, o);
  if ((t & 63) == 0) red[t >> 6] = s;
  __syncthreads();
  s = red[0] + red[1] + red[2] + red[3];
  float inv = 1.f / s;
  u16x4 o = {f2bf(p0 * inv), f2bf(p1 * inv), f2bf(p2 * inv), f2bf(p3 * inv)};
  *(u16x4*)(w + base) = o;
}

// ---------------------------------------------------------------------------
// Upsample scores2/scores4 into Acf columns 1024..3071 (bf16)
// ---------------------------------------------------------------------------
__global__ __launch_bounds__(256) void k_upsample(const uint16_t* __restrict__ s2,
                                                  const uint16_t* __restrict__ s4,
                                                  uint16_t* __restrict__ acf) {
  int g = blockIdx.x * 256 + threadIdx.x;  // 4096 rows * 256 groups
  int cg = g & 255;
  int row = g >> 8;
  int b = row >> 11, l = row & 2047;
  int c = cg * 8;
  const uint16_t* src =
      (c < 1024) ? s2 + (size_t)(b * 1024 + (l >> 1)) * 1024 + c
                 : s4 + (size_t)(b * 512 + (l >> 2)) * 1024 + (c - 1024);
  *(s16x8*)(acf + (size_t)row * 4096 + 1024 + c) = *(const s16x8*)src;
}

// ---------------------------------------------------------------------------
// Final: LayerNorm(cf)+ReLU, gate=sigmoid(gl), confidence, residual.
// ---------------------------------------------------------------------------
__global__ __launch_bounds__(256) void k_final(
    const float* __restrict__ cf, const float* __restrict__ gl,
    const float* __restrict__ x, const float* __restrict__ lns,
    const float* __restrict__ lnb, float* __restrict__ out) {
  __shared__ float red[4];
  const int row = blockIdx.x, t = threadIdx.x;
  const size_t base = (size_t)row * 1024 + t * 4;
  float4 cv = *(const float4*)(cf + base);
  float4 gv = *(const float4*)(gl + base);
  float g0 = 1.f / (1.f + __expf(-gv.x));
  float g1 = 1.f / (1.f + __expf(-gv.y));
  float g2 = 1.f / (1.f + __expf(-gv.z));
  float g3 = 1.f / (1.f + __expf(-gv.w));

  auto bsum = [&](float v) -> float {
#pragma unroll
    for (int o = 32; o > 0; o >>= 1) v += __shfl_xor(v, o);
    if ((t & 63) == 0) red[t >> 6] = v;
    __syncthreads();
    float r = red[0] + red[1] + red[2] + red[3];
    __syncthreads();
    return r;
  };
  float mu = bsum(cv.x + cv.y + cv.z + cv.w) * (1.f / 1024.f);
  float conf = bsum(g0 + g1 + g2 + g3) * (1.f / 1024.f);
  float d0 = cv.x - mu, d1 = cv.y - mu, d2 = cv.z - mu, d3 = cv.w - mu;
  float var = bsum(d0 * d0 + d1 * d1 + d2 * d2 + d3 * d3) * (1.f / 1024.f);
  float rstd = rsqrtf(var + 1e-6f);
  float4 ls = *(const float4*)(lns + t * 4);
  float4 lb = *(const float4*)(lnb + t * 4);
  float y0 = fmaxf(d0 * rstd * ls.x + lb.x, 0.f);
  float y1 = fmaxf(d1 * rstd * ls.y + lb.y, 0.f);
  float y2 = fmaxf(d2 * rstd * ls.z + lb.z, 0.f);
  float y3 = fmaxf(d3 * rstd * ls.w + lb.w, 0.f);
  float sc = sqrtf(1.f / (1024.f * conf + 1e-6f));
  float4 xv = *(const float4*)(x + base);
  float4 o1 = {xv.x + sc * g0 * y0, xv.y + sc * g1 * y1, xv.z + sc * g2 * y2,
               xv.w + sc * g3 * y3};
  *(float4*)(out + base) = o1;
  float4 o2 = {g0, g1, g2, g3};
  *(float4*)(out + 4194304 + base) = o2;
}

// ---------------------------------------------------------------------------
// Workspace layout (bytes)
// ---------------------------------------------------------------------------
static constexpr size_t OFF_QKVT = 0;            // 3 scales x 6 MiB (Wq|Wk|Wv)^T
static constexpr size_t OFF_WOT = 18 * MiBc;     // 3 x 2 MiB
static constexpr size_t OFF_W1T = 24 * MiBc;     // 8
static constexpr size_t OFF_W2T = 32 * MiBc;     // 2
static constexpr size_t OFF_EMB = 34 * MiBc;     // 2
static constexpr size_t OFF_EMT = 36 * MiBc;     // 2
static constexpr size_t OFF_XB1 = 38 * MiBc;     // 8
static constexpr size_t OFF_XB2 = 46 * MiBc;     // 4
static constexpr size_t OFF_XB4 = 50 * MiBc;     // 2
static constexpr size_t OFF_QKV = 52 * MiBc;     // 24 (reused per scale)
static constexpr size_t OFF_VT  = 76 * MiBc;     // 8
static constexpr size_t OFF_CTX = 84 * MiBc;     // 8
static constexpr size_t OFF_S2  = 92 * MiBc;     // 4
static constexpr size_t OFF_S4  = 96 * MiBc;     // 2
static constexpr size_t OFF_ACF = 98 * MiBc;     // 32
static constexpr size_t OFF_SIM = 130 * MiBc;    // 16 (fp32)
static constexpr size_t OFF_WSM = 146 * MiBc;    // 8
static constexpr size_t OFF_CF  = 154 * MiBc;    // 16 (fp32)
static constexpr size_t OFF_BQKV = 170 * MiBc;   // 36 KB (gate logits in d_out)
static constexpr size_t WS_NEED = 186 * MiBc;

static constexpr float QSC = 0.125f * 1.44269504f;  // 1/sqrt(64) * log2(e)

extern "C" void kernel_launch(void* const* d_in, const int* in_sizes, int n_in,
                              void* d_out, int out_size, void* d_ws,
                              size_t ws_size, hipStream_t stream) {
  (void)in_sizes; (void)n_in; (void)out_size;
  const float* x  = (const float*)d_in[0];
  const float* em = (const float*)d_in[1];
  const float* Wq = (const float*)d_in[2];
  const float* bq = (const float*)d_in[3];
  const float* Wk = (const float*)d_in[4];
  const float* bk = (const float*)d_in[5];
  const float* Wv = (const float*)d_in[6];
  const float* bv = (const float*)d_in[7];
  const float* Wo = (const float*)d_in[8];
  const float* bo = (const float*)d_in[9];
  const float* W1 = (const float*)d_in[10];
  const float* b1 = (const float*)d_in[11];
  const float* lns = (const float*)d_in[12];
  const float* lnb = (const float*)d_in[13];
  const float* W2 = (const float*)d_in[14];
  const float* b2 = (const float*)d_in[15];
  float* out = (float*)d_out;

  if (ws_size < WS_NEED) {  // sentinel: makes ws-too-small distinguishable
    hipMemsetAsync(d_out, 0x7f, 4, stream);
    return;
  }
  uint8_t* w8 = (uint8_t*)d_ws;
  auto U16 = [&](size_t off) { return (uint16_t*)(w8 + off); };
  uint16_t* QKVT = U16(OFF_QKVT);
  uint16_t* WOT = U16(OFF_WOT);
  uint16_t* W1T = U16(OFF_W1T);
  uint16_t* W2T = U16(OFF_W2T);
  uint16_t* EMB = U16(OFF_EMB);
  uint16_t* EMT = U16(OFF_EMT);
  uint16_t* XB1 = U16(OFF_XB1);
  uint16_t* XB2 = U16(OFF_XB2);
  uint16_t* XB4 = U16(OFF_XB4);
  uint16_t* QKVb = U16(OFF_QKV);
  uint16_t* VTb = U16(OFF_VT);
  uint16_t* CTX = U16(OFF_CTX);
  uint16_t* S2b = U16(OFF_S2);
  uint16_t* S4b = U16(OFF_S4);
  uint16_t* ACF = U16(OFF_ACF);
  float* SIM = (float*)(w8 + OFF_SIM);
  uint16_t* WSM = U16(OFF_WSM);
  float* CF = (float*)(w8 + OFF_CF);
  float* BQKV = (float*)(w8 + OFF_BQKV);
  float* GL = out + 4194304;  // gate logits in-place in d_out gate region

  const size_t MM = 1024 * 1024;
  const size_t SC3 = 3 * MM;  // elements per packed QKV^T scale

  // 1) weight prep: transposes to B^T layout (QKV packed), EM bf16, biases
  TD14 td{};
  for (int i = 0; i < 3; ++i) {
    td.d[i]     = {Wq + (size_t)i * MM, QKVT + (size_t)i * SC3};
    td.d[3 + i] = {Wk + (size_t)i * MM, QKVT + (size_t)i * SC3 + MM};
    td.d[6 + i] = {Wv + (size_t)i * MM, QKVT + (size_t)i * SC3 + 2 * MM};
    td.d[9 + i] = {Wo + (size_t)i * MM, WOT + (size_t)i * MM};
  }
  td.d[12] = {W2, W2T};
  td.d[13] = {em, EMT};
  k_transpose<<<dim3(1024, 14), 256, 0, stream>>>(td, 1024, 1024);
  TD14 t1{};
  t1.d[0] = {W1, W1T};
  k_transpose<<<dim3(4096, 1), 256, 0, stream>>>(t1, 4096, 1024);
  k_f2bf4<<<dim3(1024), 256, 0, stream>>>(em, EMB);
  k_biaspack<<<dim3(36), 256, 0, stream>>>(bq, bk, bv, BQKV);
  k_down<<<dim3(4096), 256, 0, stream>>>(x, XB1, XB2, XB4);

  // 2) per-scale self-attention (merged QKV GEMM, N=3072; Q cols post-scaled
  //    by QSC so attention scores land directly in the exp2 domain)
  for (int i = 0; i < 3; ++i) {
    const int S = 2048 >> i;
    const int R = 2 * S;
    const uint16_t* xb = (i == 0) ? XB1 : (i == 1) ? XB2 : XB4;
    k_gemm<<<dim3(24, R / 128), 256, 0, stream>>>(
        xb, QKVT + (size_t)i * SC3, BQKV + i * 3072, QKVb, R, 3072, 1024, 3072,
        1.f, QSC, 1024, 1);
    k_vtrans<<<dim3(32 * (S / 64)), 256, 0, stream>>>(QKVb + 2048, VTb, S, 3072);
    k_attn<<<dim3(32 * (S / 32)), 256, 0, stream>>>(QKVb, VTb, CTX, S);
    dim3 gg(8, R / 128);
    if (i == 0)
      k_gemm<<<gg, 256, 0, stream>>>(CTX, WOT, bo, ACF, R, 1024, 1024, 4096,
                                     1.f, 1.f, 0, 1);
    else if (i == 1)
      k_gemm<<<gg, 256, 0, stream>>>(CTX, WOT + MM, bo + 1024, S2b, R, 1024,
                                     1024, 1024, 1.f, 1.f, 0, 1);
    else
      k_gemm<<<gg, 256, 0, stream>>>(CTX, WOT + 2 * MM, bo + 2048, S4b, R, 1024,
                                     1024, 1024, 1.f, 1.f, 0, 1);
  }

  // 3) memory path: sim -> softmax -> readback (into Acf cols 3072..4095)
  k_gemm<<<dim3(8, 32), 256, 0, stream>>>(XB1, EMB, nullptr, SIM, 4096, 1024,
                                          1024, 1024, 0.03125f, 1.f, 0, 0);
  k_softmax<<<dim3(4096), 256, 0, stream>>>(SIM, WSM);
  k_gemm<<<dim3(8, 32), 256, 0, stream>>>(WSM, EMT, nullptr, ACF + 3072, 4096,
                                          1024, 1024, 4096, 1.f, 1.f, 0, 1);
  k_upsample<<<dim3(4096), 256, 0, stream>>>(S2b, S4b, ACF);

  // 4) cf GEMM (K=4096), gate GEMM, fused LN/gate/residual
  k_gemm<<<dim3(8, 32), 256, 0, stream>>>(ACF, W1T, b1, CF, 4096, 1024, 4096,
                                          1024, 1.f, 1.f, 0, 0);
  k_gemm<<<dim3(8, 32), 256, 0, stream>>>(XB1, W2T, b2, GL, 4096, 1024, 1024,
                                          1024, 1.f, 1.f, 0, 0);
  k_final<<<dim3(4096), 256, 0, stream>>>(CF, GL, x, lns, lnb, out);
}

// Round 9
// 729.964 us; speedup vs baseline: 1.1209x; 1.1079x over previous
//
#include <hip/hip_runtime.h>
#include <stdint.h>

// ---------------------------------------------------------------------------
// ErrorCorrectionModule on MI355X (gfx950)
// B=2, L=2048, H=1024, NH=16, HD=64, M=1024, SCALES=(1,2,4)
// R8: attn rewrite — LDS-shared K/V. Block = 4 waves x 32 q-rows = 128 q-rows
// sharing each 64-k K/V tile staged via coalesced global_load_lds (16B/lane,
// pre-swizzled source col; XOR 16B-slot swizzle on LDS reads — both-sides
// rule). Replaces the scattered 16-row L2 gathers that pinned R4/R6/R7 at
// ~190us. K/V L2 traffic /4 and coalesced. Softmax numerics = R6 (exp2 +
// exact defer-rescale). No split-K merge.
// ---------------------------------------------------------------------------

#define MiBc ((size_t)1 << 20)

using s16x8 = __attribute__((ext_vector_type(8))) short;   // 8 bf16 (4 VGPR)
using s16x4 = __attribute__((ext_vector_type(4))) short;   // 4 bf16 (2 VGPR)
using u16x4 = __attribute__((ext_vector_type(4))) unsigned short;
using f32x4 = __attribute__((ext_vector_type(4))) float;

__device__ __forceinline__ uint16_t f2bf(float f) {
  uint32_t u = __float_as_uint(f);
  return (uint16_t)((u + 0x7fffu + ((u >> 16) & 1u)) >> 16);  // RNE
}

__device__ __forceinline__ float fexp2(float x) {
  return __builtin_amdgcn_exp2f(x);  // raw v_exp_f32 (2^x)
}

// async global->LDS, 16B per lane; LDS dest is wave-uniform base + lane*16
__device__ __forceinline__ void load_lds16(const uint16_t* g, uint16_t* l) {
  __builtin_amdgcn_global_load_lds(
      (const __attribute__((address_space(1))) void*)(const void*)g,
      (__attribute__((address_space(3))) void*)(void*)l, 16, 0, 0);
}

// ---------------------------------------------------------------------------
// Transpose fp32 [R][C] -> bf16 [C][R]  (B^T weight layout builder)
// ---------------------------------------------------------------------------
struct TD { const float* in; uint16_t* out; };
struct TD14 { TD d[14]; };

__global__ __launch_bounds__(256) void k_transpose(TD14 ds, int R, int C) {
  const float* in = ds.d[blockIdx.y].in;
  uint16_t* out = ds.d[blockIdx.y].out;
  const int nTC = C >> 5;
  const int bi = blockIdx.x / nTC, bj = blockIdx.x % nTC;
  __shared__ float t[32][33];
  const int tx = threadIdx.x & 31, ty = threadIdx.x >> 5;  // ty 0..7
#pragma unroll
  for (int p = 0; p < 4; ++p) {
    int r = bi * 32 + ty + p * 8;
    t[ty + p * 8][tx] = in[(size_t)r * C + bj * 32 + tx];
  }
  __syncthreads();
#pragma unroll
  for (int p = 0; p < 4; ++p) {
    int c = bj * 32 + ty + p * 8;
    out[(size_t)c * R + bi * 32 + tx] = f2bf(t[tx][ty + p * 8]);
  }
}

// plain fp32 -> bf16 convert (error_memory, kept row-major for sim's B^T)
__global__ __launch_bounds__(256) void k_f2bf4(const float* __restrict__ in,
                                               uint16_t* __restrict__ out) {
  int i = (blockIdx.x * 256 + threadIdx.x) * 4;
  float4 v = *(const float4*)(in + i);
  u16x4 o = {f2bf(v.x), f2bf(v.y), f2bf(v.z), f2bf(v.w)};
  *(u16x4*)(out + i) = o;
}

// pack bq|bk|bv (3 scales) into BQKV[3][3072]
__global__ __launch_bounds__(256) void k_biaspack(const float* __restrict__ bq,
                                                  const float* __restrict__ bk,
                                                  const float* __restrict__ bv,
                                                  float* __restrict__ dst) {
  int g = blockIdx.x * 256 + threadIdx.x;  // 9216
  int i = g / 3072, j = g - i * 3072;
  const float* src = (j < 1024)   ? bq + i * 1024 + j
                     : (j < 2048) ? bk + i * 1024 + (j - 1024)
                                  : bv + i * 1024 + (j - 2048);
  dst[g] = *src;
}

// ---------------------------------------------------------------------------
// Downsample x (fp32 [B,2048,1024]) -> bf16 scale-1/2/4 averaged copies
// ---------------------------------------------------------------------------
__global__ __launch_bounds__(256) void k_down(const float* __restrict__ x,
                                              uint16_t* __restrict__ x1,
                                              uint16_t* __restrict__ x2,
                                              uint16_t* __restrict__ x4) {
  int g = blockIdx.x * 256 + threadIdx.x;  // 2*512*1024 threads
  int c = g & 1023;
  int l4 = (g >> 10) & 511;
  int b = g >> 19;
  const float* xp = x + (size_t)(b * 2048 + l4 * 4) * 1024 + c;
  float a0 = xp[0], a1 = xp[1024], a2 = xp[2048], a3 = xp[3072];
  size_t r1 = (size_t)(b * 2048 + l4 * 4) * 1024 + c;
  x1[r1] = f2bf(a0);
  x1[r1 + 1024] = f2bf(a1);
  x1[r1 + 2048] = f2bf(a2);
  x1[r1 + 3072] = f2bf(a3);
  size_t r2 = (size_t)(b * 1024 + l4 * 2) * 1024 + c;
  x2[r2] = f2bf(0.5f * (a0 + a1));
  x2[r2 + 1024] = f2bf(0.5f * (a2 + a3));
  x4[(size_t)(b * 512 + l4) * 1024 + c] = f2bf(0.25f * (a0 + a1 + a2 + a3));
}

// ---------------------------------------------------------------------------
// bf16 GEMM, B^T input layout (BT[n][k]). v = (acc*scale + bias) * post,
// post = qscale for cols < qcols else 1 (used to pre-scale Q into exp2 dom).
// 128x128 tile, BK=32, 4 waves (2x2), 4x4 16x16x32 MFMA frags per wave.
// ---------------------------------------------------------------------------
__global__ __launch_bounds__(256) void k_gemm(
    const uint16_t* __restrict__ A, const uint16_t* __restrict__ BT,
    const float* __restrict__ bias, void* __restrict__ C, int M, int N, int K,
    int ldc, float scale, float qscale, int qcols, int out_bf16) {
  __shared__ __align__(16) uint16_t Al[128 * 32];
  __shared__ __align__(16) uint16_t Bl[128 * 32];
  const int tid = threadIdx.x;
  const int wave = tid >> 6, lane = tid & 63;
  const int wr = wave >> 1, wc = wave & 1;
  const int lr = lane & 15, lg = lane >> 4;
  const int bM = blockIdx.y * 128, bN = blockIdx.x * 128;
  (void)M; (void)N;

  f32x4 acc[4][4] = {};

  for (int k0 = 0; k0 < K; k0 += 32) {
    __syncthreads();  // previous tile's frag reads done before overwrite
#pragma unroll
    for (int j = 0; j < 2; ++j) {
      int ck = wave * 2 + j;          // 8 chunks of 1024B per tile
      int p = ck * 64 + lane;         // 16B chunk index
      int row = p >> 2, kq = p & 3;
      load_lds16(A + (size_t)(bM + row) * K + k0 + kq * 8, &Al[ck * 512]);
      load_lds16(BT + (size_t)(bN + row) * K + k0 + kq * 8, &Bl[ck * 512]);
    }
    __syncthreads();  // vmcnt(0) drain -> LDS ready
    s16x8 af[4], bfr[4];
#pragma unroll
    for (int i = 0; i < 4; ++i)
      af[i] = *(const s16x8*)&Al[(wr * 64 + i * 16 + lr) * 32 + lg * 8];
#pragma unroll
    for (int i = 0; i < 4; ++i)
      bfr[i] = *(const s16x8*)&Bl[(wc * 64 + i * 16 + lr) * 32 + lg * 8];
#pragma unroll
    for (int i = 0; i < 4; ++i)
#pragma unroll
      for (int jn = 0; jn < 4; ++jn)
        acc[i][jn] = __builtin_amdgcn_mfma_f32_16x16x32_bf16(
            af[i], bfr[jn], acc[i][jn], 0, 0, 0);
  }

  // epilogue: D layout col=lane&15, row=(lane>>4)*4+reg  [m89-verified]
#pragma unroll
  for (int i = 0; i < 4; ++i) {
    int rg = bM + wr * 64 + i * 16 + lg * 4;
#pragma unroll
    for (int jn = 0; jn < 4; ++jn) {
      int cg = bN + wc * 64 + jn * 16 + lr;
      float bv = bias ? bias[cg] : 0.f;
      float post = (cg < qcols) ? qscale : 1.f;
#pragma unroll
      for (int r = 0; r < 4; ++r) {
        float v = (acc[i][jn][r] * scale + bv) * post;
        if (out_bf16)
          ((uint16_t*)C)[(size_t)(rg + r) * ldc + cg] = f2bf(v);
        else
          ((float*)C)[(size_t)(rg + r) * ldc + cg] = v;
      }
    }
  }
}

// ---------------------------------------------------------------------------
// V transpose: v bf16 [B*S][ld] (col offset pre-applied) -> vt[(bh)*64+d][S]
// ---------------------------------------------------------------------------
__global__ __launch_bounds__(256) void k_vtrans(const uint16_t* __restrict__ v,
                                                uint16_t* __restrict__ vt,
                                                int S, int ld) {
  const int nKT = S >> 6;
  const int bh = blockIdx.x / nKT, kt = blockIdx.x % nKT;
  const int b = bh >> 4, h = bh & 15;
  __shared__ uint16_t t[64][65];
  for (int i = threadIdx.x; i < 4096; i += 256) {
    int kk = i >> 6, dd = i & 63;
    t[dd][kk] = v[(size_t)(b * S + kt * 64 + kk) * ld + h * 64 + dd];
  }
  __syncthreads();
  for (int i = threadIdx.x; i < 4096; i += 256) {
    int dd = i >> 6, kk = i & 63;
    vt[((size_t)(bh * 64) + dd) * S + kt * 64 + kk] = t[dd][kk];
  }
}

// ---------------------------------------------------------------------------
// Flash attention, LDS-shared K/V. qkv: [B*S][3072] (Q cols pre-scaled by
// 0.125*log2e -> exp2 domain), vt: [(b*16+h)*64+d][S].
// Block (256T) = (bh, 128 q-rows); wave wv owns rows qb*128 + wv*32 .. +32.
// Per 64-k tile: cooperative coalesced stage of K[64][64] and V^T[64][64]
// into LDS (16B slots; source col pre-swizzled with slot^=(row&7) so the
// swizzled ds_reads below see the right data — both-sides rule). Inner loop
// reads LDS; softmax = R6 numerics (exp2 domain + exact defer-rescale).
// ---------------------------------------------------------------------------
__global__ __launch_bounds__(256) void k_attn(const uint16_t* __restrict__ qkv,
                                              const uint16_t* __restrict__ vt,
                                              uint16_t* __restrict__ ctx,
                                              int S) {
  __shared__ __align__(16) uint16_t Kl[64 * 64];  // 8 KB
  __shared__ __align__(16) uint16_t Vl[64 * 64];  // 8 KB
  const int lane = threadIdx.x & 63;
  const int wv = threadIdx.x >> 6;
  const int nQB = S >> 7;  // 128 q-rows per block
  const int bh = blockIdx.x / nQB;  // b*16+h
  const int qb = blockIdx.x % nQB;
  const int h = bh & 15, b = bh >> 4;
  const int lr = lane & 15, lg = lane >> 4;

  const int qrow0 = qb * 128 + wv * 32;
  const uint16_t* qp =
      qkv + (size_t)(b * S + qrow0 + lr) * 3072 + h * 64 + lg * 8;
  s16x8 qf0[2], qf1[2];
  qf0[0] = *(const s16x8*)qp;
  qf1[0] = *(const s16x8*)(qp + 32);
  qf0[1] = *(const s16x8*)(qp + 16 * 3072);
  qf1[1] = *(const s16x8*)(qp + 16 * 3072 + 32);
  const uint16_t* kg = qkv + (size_t)(b * S) * 3072 + 1024 + h * 64;
  const uint16_t* vg = vt + (size_t)(bh * 64) * S;

  f32x4 acc[2][4] = {};
  float mS[2] = {-1e30f, -1e30f};
  float lS[2] = {0.f, 0.f};

  // staging lane geometry: row_local = ck*8 + (lane>>3), 16B slot = lane&7,
  // source slot pre-swizzled by row&7 ( == (lane>>3)&7 since ck*8 = 0 mod 8)
  const int srl = lane >> 3;                 // row within 8-row chunk
  const int ssl = (lane & 7) ^ (srl & 7);    // pre-swizzled source slot

  const int nKV = S >> 6;
  for (int blk = 0; blk < nKV; ++blk) {
    __syncthreads();  // prior mini-tiles done reading LDS
#pragma unroll
    for (int j = 0; j < 4; ++j) {
      int ck = wv * 4 + j;  // 0..15 : 0-7 K chunks, 8-15 V chunks
      int rl = ((ck & 7) << 3) + srl;
      if (ck < 8)
        load_lds16(kg + (size_t)(blk * 64 + rl) * 3072 + ssl * 8,
                   &Kl[(ck & 7) * 512]);
      else
        load_lds16(vg + (size_t)rl * S + blk * 64 + ssl * 8,
                   &Vl[(ck & 7) * 512]);
    }
    __syncthreads();  // vmcnt drain -> LDS tiles ready

#pragma unroll
    for (int kt = 0; kt < 4; ++kt) {
      const int r = kt * 16 + lr;
      const int sw = r & 7;
      s16x8 K0 = *(const s16x8*)&Kl[r * 64 + ((lg ^ sw) << 3)];
      s16x8 K1 = *(const s16x8*)&Kl[r * 64 + (((lg + 4) ^ sw) << 3)];
      s16x4 vf[4];
#pragma unroll
      for (int c = 0; c < 4; ++c) {
        int d = c * 16 + lr;
        int s16 = (kt << 1) | (lg >> 1);
        vf[c] = *(const s16x4*)&Vl[d * 64 + (((s16 ^ (d & 7)) << 3) |
                                             ((lg & 1) << 2))];
      }
#pragma unroll
      for (int f = 0; f < 2; ++f) {
        f32x4 st = {};
        st = __builtin_amdgcn_mfma_f32_16x16x32_bf16(K0, qf0[f], st, 0, 0, 0);
        st = __builtin_amdgcn_mfma_f32_16x16x32_bf16(K1, qf1[f], st, 0, 0, 0);
        float tmax = fmaxf(fmaxf(st[0], st[1]), fmaxf(st[2], st[3]));
        tmax = fmaxf(tmax, __shfl_xor(tmax, 16));
        tmax = fmaxf(tmax, __shfl_xor(tmax, 32));
        if (!__all(tmax <= mS[f])) {
          float mn = fmaxf(mS[f], tmax);
          float fac = fexp2(mS[f] - mn);
          mS[f] = mn;
          lS[f] *= fac;
#pragma unroll
          for (int c = 0; c < 4; ++c) acc[f][c] *= fac;
        }
        float p0 = fexp2(st[0] - mS[f]), p1 = fexp2(st[1] - mS[f]);
        float p2 = fexp2(st[2] - mS[f]), p3 = fexp2(st[3] - mS[f]);
        lS[f] += (p0 + p1) + (p2 + p3);
        s16x4 pb;
        pb[0] = (short)f2bf(p0);
        pb[1] = (short)f2bf(p1);
        pb[2] = (short)f2bf(p2);
        pb[3] = (short)f2bf(p3);
#pragma unroll
        for (int c = 0; c < 4; ++c)
          acc[f][c] = __builtin_amdgcn_mfma_f32_16x16x16bf16_1k(
              vf[c], pb, acc[f][c], 0, 0, 0);
      }
    }
  }

#pragma unroll
  for (int f = 0; f < 2; ++f) {
    float l = lS[f];
    l += __shfl_xor(l, 16);
    l += __shfl_xor(l, 32);
    const float inv = 1.f / l;
    uint16_t* crow =
        ctx + (size_t)(b * S + qrow0 + f * 16 + lr) * 1024 + h * 64;
#pragma unroll
    for (int c = 0; c < 4; ++c) {
      u16x4 o;
#pragma unroll
      for (int r = 0; r < 4; ++r) o[r] = f2bf(acc[f][c][r] * inv);
      *(u16x4*)(crow + c * 16 + lg * 4) = o;
    }
  }
}

// ---------------------------------------------------------------------------
// Row softmax over M=1024: sim fp32 [4096][1024] -> weights bf16
// ---------------------------------------------------------------------------
__global__ __launch_bounds__(256) void k_softmax(const float* __restrict__ sim,
                                                 uint16_t* __restrict__ w) {
  __shared__ float red[4];
  const int row = blockIdx.x, t = threadIdx.x;
  const size_t base = (size_t)row * 1024 + t * 4;
  float4 v = *(const float4*)(sim + base);
  float mx = fmaxf(fmaxf(v.x, v.y), fmaxf(v.z, v.w));
#pragma unroll
  for (int o = 32; o > 0; o >>= 1) mx = fmaxf(mx, __shfl_xor(mx, o));
  if ((t & 63) == 0) red[t >> 6] = mx;
  __syncthreads();
  mx = fmaxf(fmaxf(red[0], red[1]), fmaxf(red[2], red[3]));
  __syncthreads();
  float p0 = __expf(v.x - mx), p1 = __expf(v.y - mx);
  float p2 = __expf(v.z - mx), p3 = __expf(v.w - mx);
  float s = p0 + p1 + p2 + p3;
#pragma unroll
  for (int o = 32; o > 0; o >>= 1) s += __shfl_xor(s, o);
  if ((t & 63) == 0) red[t >> 6] = s;
  __syncthreads();
  s = red[0] + red[1] + red[2] + red[3];
  float inv = 1.f / s;
  u16x4 o = {f2bf(p0 * inv), f2bf(p1 * inv), f2bf(p2 * inv), f2bf(p3 * inv)};
  *(u16x4*)(w + base) = o;
}

// ---------------------------------------------------------------------------
// Upsample scores2/scores4 into Acf columns 1024..3071 (bf16)
// ---------------------------------------------------------------------------
__global__ __launch_bounds__(256) void k_upsample(const uint16_t* __restrict__ s2,
                                                  const uint16_t* __restrict__ s4,
                                                  uint16_t* __restrict__ acf) {
  int g = blockIdx.x * 256 + threadIdx.x;  // 4096 rows * 256 groups
  int cg = g & 255;
  int row = g >> 8;
  int b = row >> 11, l = row & 2047;
  int c = cg * 8;
  const uint16_t* src =
      (c < 1024) ? s2 + (size_t)(b * 1024 + (l >> 1)) * 1024 + c
                 : s4 + (size_t)(b * 512 + (l >> 2)) * 1024 + (c - 1024);
  *(s16x8*)(acf + (size_t)row * 4096 + 1024 + c) = *(const s16x8*)src;
}

// ---------------------------------------------------------------------------
// Final: LayerNorm(cf)+ReLU, gate=sigmoid(gl), confidence, residual.
// ---------------------------------------------------------------------------
__global__ __launch_bounds__(256) void k_final(
    const float* __restrict__ cf, const float* __restrict__ gl,
    const float* __restrict__ x, const float* __restrict__ lns,
    const float* __restrict__ lnb, float* __restrict__ out) {
  __shared__ float red[4];
  const int row = blockIdx.x, t = threadIdx.x;
  const size_t base = (size_t)row * 1024 + t * 4;
  float4 cv = *(const float4*)(cf + base);
  float4 gv = *(const float4*)(gl + base);
  float g0 = 1.f / (1.f + __expf(-gv.x));
  float g1 = 1.f / (1.f + __expf(-gv.y));
  float g2 = 1.f / (1.f + __expf(-gv.z));
  float g3 = 1.f / (1.f + __expf(-gv.w));

  auto bsum = [&](float v) -> float {
#pragma unroll
    for (int o = 32; o > 0; o >>= 1) v += __shfl_xor(v, o);
    if ((t & 63) == 0) red[t >> 6] = v;
    __syncthreads();
    float r = red[0] + red[1] + red[2] + red[3];
    __syncthreads();
    return r;
  };
  float mu = bsum(cv.x + cv.y + cv.z + cv.w) * (1.f / 1024.f);
  float conf = bsum(g0 + g1 + g2 + g3) * (1.f / 1024.f);
  float d0 = cv.x - mu, d1 = cv.y - mu, d2 = cv.z - mu, d3 = cv.w - mu;
  float var = bsum(d0 * d0 + d1 * d1 + d2 * d2 + d3 * d3) * (1.f / 1024.f);
  float rstd = rsqrtf(var + 1e-6f);
  float4 ls = *(const float4*)(lns + t * 4);
  float4 lb = *(const float4*)(lnb + t * 4);
  float y0 = fmaxf(d0 * rstd * ls.x + lb.x, 0.f);
  float y1 = fmaxf(d1 * rstd * ls.y + lb.y, 0.f);
  float y2 = fmaxf(d2 * rstd * ls.z + lb.z, 0.f);
  float y3 = fmaxf(d3 * rstd * ls.w + lb.w, 0.f);
  float sc = sqrtf(1.f / (1024.f * conf + 1e-6f));
  float4 xv = *(const float4*)(x + base);
  float4 o1 = {xv.x + sc * g0 * y0, xv.y + sc * g1 * y1, xv.z + sc * g2 * y2,
               xv.w + sc * g3 * y3};
  *(float4*)(out + base) = o1;
  float4 o2 = {g0, g1, g2, g3};
  *(float4*)(out + 4194304 + base) = o2;
}

// ---------------------------------------------------------------------------
// Workspace layout (bytes)
// ---------------------------------------------------------------------------
static constexpr size_t OFF_QKVT = 0;            // 3 scales x 6 MiB (Wq|Wk|Wv)^T
static constexpr size_t OFF_WOT = 18 * MiBc;     // 3 x 2 MiB
static constexpr size_t OFF_W1T = 24 * MiBc;     // 8
static constexpr size_t OFF_W2T = 32 * MiBc;     // 2
static constexpr size_t OFF_EMB = 34 * MiBc;     // 2
static constexpr size_t OFF_EMT = 36 * MiBc;     // 2
static constexpr size_t OFF_XB1 = 38 * MiBc;     // 8
static constexpr size_t OFF_XB2 = 46 * MiBc;     // 4
static constexpr size_t OFF_XB4 = 50 * MiBc;     // 2
static constexpr size_t OFF_QKV = 52 * MiBc;     // 24 (reused per scale)
static constexpr size_t OFF_VT  = 76 * MiBc;     // 8
static constexpr size_t OFF_CTX = 84 * MiBc;     // 8
static constexpr size_t OFF_S2  = 92 * MiBc;     // 4
static constexpr size_t OFF_S4  = 96 * MiBc;     // 2
static constexpr size_t OFF_ACF = 98 * MiBc;     // 32
static constexpr size_t OFF_SIM = 130 * MiBc;    // 16 (fp32)
static constexpr size_t OFF_WSM = 146 * MiBc;    // 8
static constexpr size_t OFF_CF  = 154 * MiBc;    // 16 (fp32)
static constexpr size_t OFF_BQKV = 170 * MiBc;   // 36 KB (gate logits in d_out)
static constexpr size_t WS_NEED = 186 * MiBc;

static constexpr float QSC = 0.125f * 1.44269504f;  // 1/sqrt(64) * log2(e)

extern "C" void kernel_launch(void* const* d_in, const int* in_sizes, int n_in,
                              void* d_out, int out_size, void* d_ws,
                              size_t ws_size, hipStream_t stream) {
  (void)in_sizes; (void)n_in; (void)out_size;
  const float* x  = (const float*)d_in[0];
  const float* em = (const float*)d_in[1];
  const float* Wq = (const float*)d_in[2];
  const float* bq = (const float*)d_in[3];
  const float* Wk = (const float*)d_in[4];
  const float* bk = (const float*)d_in[5];
  const float* Wv = (const float*)d_in[6];
  const float* bv = (const float*)d_in[7];
  const float* Wo = (const float*)d_in[8];
  const float* bo = (const float*)d_in[9];
  const float* W1 = (const float*)d_in[10];
  const float* b1 = (const float*)d_in[11];
  const float* lns = (const float*)d_in[12];
  const float* lnb = (const float*)d_in[13];
  const float* W2 = (const float*)d_in[14];
  const float* b2 = (const float*)d_in[15];
  float* out = (float*)d_out;

  if (ws_size < WS_NEED) {  // sentinel: makes ws-too-small distinguishable
    hipMemsetAsync(d_out, 0x7f, 4, stream);
    return;
  }
  uint8_t* w8 = (uint8_t*)d_ws;
  auto U16 = [&](size_t off) { return (uint16_t*)(w8 + off); };
  uint16_t* QKVT = U16(OFF_QKVT);
  uint16_t* WOT = U16(OFF_WOT);
  uint16_t* W1T = U16(OFF_W1T);
  uint16_t* W2T = U16(OFF_W2T);
  uint16_t* EMB = U16(OFF_EMB);
  uint16_t* EMT = U16(OFF_EMT);
  uint16_t* XB1 = U16(OFF_XB1);
  uint16_t* XB2 = U16(OFF_XB2);
  uint16_t* XB4 = U16(OFF_XB4);
  uint16_t* QKVb = U16(OFF_QKV);
  uint16_t* VTb = U16(OFF_VT);
  uint16_t* CTX = U16(OFF_CTX);
  uint16_t* S2b = U16(OFF_S2);
  uint16_t* S4b = U16(OFF_S4);
  uint16_t* ACF = U16(OFF_ACF);
  float* SIM = (float*)(w8 + OFF_SIM);
  uint16_t* WSM = U16(OFF_WSM);
  float* CF = (float*)(w8 + OFF_CF);
  float* BQKV = (float*)(w8 + OFF_BQKV);
  float* GL = out + 4194304;  // gate logits in-place in d_out gate region

  const size_t MM = 1024 * 1024;
  const size_t SC3 = 3 * MM;  // elements per packed QKV^T scale

  // 1) weight prep: transposes to B^T layout (QKV packed), EM bf16, biases
  TD14 td{};
  for (int i = 0; i < 3; ++i) {
    td.d[i]     = {Wq + (size_t)i * MM, QKVT + (size_t)i * SC3};
    td.d[3 + i] = {Wk + (size_t)i * MM, QKVT + (size_t)i * SC3 + MM};
    td.d[6 + i] = {Wv + (size_t)i * MM, QKVT + (size_t)i * SC3 + 2 * MM};
    td.d[9 + i] = {Wo + (size_t)i * MM, WOT + (size_t)i * MM};
  }
  td.d[12] = {W2, W2T};
  td.d[13] = {em, EMT};
  k_transpose<<<dim3(1024, 14), 256, 0, stream>>>(td, 1024, 1024);
  TD14 t1{};
  t1.d[0] = {W1, W1T};
  k_transpose<<<dim3(4096, 1), 256, 0, stream>>>(t1, 4096, 1024);
  k_f2bf4<<<dim3(1024), 256, 0, stream>>>(em, EMB);
  k_biaspack<<<dim3(36), 256, 0, stream>>>(bq, bk, bv, BQKV);
  k_down<<<dim3(4096), 256, 0, stream>>>(x, XB1, XB2, XB4);

  // 2) per-scale self-attention (merged QKV GEMM, N=3072; Q cols post-scaled
  //    by QSC so attention scores land directly in the exp2 domain)
  for (int i = 0; i < 3; ++i) {
    const int S = 2048 >> i;
    const int R = 2 * S;
    const uint16_t* xb = (i == 0) ? XB1 : (i == 1) ? XB2 : XB4;
    k_gemm<<<dim3(24, R / 128), 256, 0, stream>>>(
        xb, QKVT + (size_t)i * SC3, BQKV + i * 3072, QKVb, R, 3072, 1024, 3072,
        1.f, QSC, 1024, 1);
    k_vtrans<<<dim3(32 * (S / 64)), 256, 0, stream>>>(QKVb + 2048, VTb, S, 3072);
    k_attn<<<dim3(32 * (S / 128)), 256, 0, stream>>>(QKVb, VTb, CTX, S);
    dim3 gg(8, R / 128);
    if (i == 0)
      k_gemm<<<gg, 256, 0, stream>>>(CTX, WOT, bo, ACF, R, 1024, 1024, 4096,
                                     1.f, 1.f, 0, 1);
    else if (i == 1)
      k_gemm<<<gg, 256, 0, stream>>>(CTX, WOT + MM, bo + 1024, S2b, R, 1024,
                                     1024, 1024, 1.f, 1.f, 0, 1);
    else
      k_gemm<<<gg, 256, 0, stream>>>(CTX, WOT + 2 * MM, bo + 2048, S4b, R, 1024,
                                     1024, 1024, 1.f, 1.f, 0, 1);
  }

  // 3) memory path: sim -> softmax -> readback (into Acf cols 3072..4095)
  k_gemm<<<dim3(8, 32), 256, 0, stream>>>(XB1, EMB, nullptr, SIM, 4096, 1024,
                                          1024, 1024, 0.03125f, 1.f, 0, 0);
  k_softmax<<<dim3(4096), 256, 0, stream>>>(SIM, WSM);
  k_gemm<<<dim3(8, 32), 256, 0, stream>>>(WSM, EMT, nullptr, ACF + 3072, 4096,
                                          1024, 1024, 4096, 1.f, 1.f, 0, 1);
  k_upsample<<<dim3(4096), 256, 0, stream>>>(S2b, S4b, ACF);

  // 4) cf GEMM (K=4096), gate GEMM, fused LN/gate/residual
  k_gemm<<<dim3(8, 32), 256, 0, stream>>>(ACF, W1T, b1, CF, 4096, 1024, 4096,
                                          1024, 1.f, 1.f, 0, 0);
  k_gemm<<<dim3(8, 32), 256, 0, stream>>>(XB1, W2T, b2, GL, 4096, 1024, 1024,
                                          1024, 1.f, 1.f, 0, 0);
  k_final<<<dim3(4096), 256, 0, stream>>>(CF, GL, x, lns, lnb, out);
}

// Round 10
// 687.447 us; speedup vs baseline: 1.1902x; 1.0618x over previous
//
#include <hip/hip_runtime.h>
#include <stdint.h>

// ---------------------------------------------------------------------------
// ErrorCorrectionModule on MI355X (gfx950)
// B=2, L=2048, H=1024, NH=16, HD=64, M=1024, SCALES=(1,2,4)
// R9: GEMM occupancy push. New k_gemm64 (BM=64 x BN=128 tile, same verified
// chunk/frag/epilogue math) used for every GEMM whose 128^2 grid was <=1
// block/CU (Wo x3, sim, readback, cf, gate, QKV s1/s2). Doubles their grids
// to ~2 blocks/CU so the 2-barrier m97 loop has overlap partners.
// attn = R8 (LDS-shared K/V, 110us @S=2048). Numerics unchanged everywhere.
// ---------------------------------------------------------------------------

#define MiBc ((size_t)1 << 20)

using s16x8 = __attribute__((ext_vector_type(8))) short;   // 8 bf16 (4 VGPR)
using s16x4 = __attribute__((ext_vector_type(4))) short;   // 4 bf16 (2 VGPR)
using u16x4 = __attribute__((ext_vector_type(4))) unsigned short;
using f32x4 = __attribute__((ext_vector_type(4))) float;

__device__ __forceinline__ uint16_t f2bf(float f) {
  uint32_t u = __float_as_uint(f);
  return (uint16_t)((u + 0x7fffu + ((u >> 16) & 1u)) >> 16);  // RNE
}

__device__ __forceinline__ float fexp2(float x) {
  return __builtin_amdgcn_exp2f(x);  // raw v_exp_f32 (2^x)
}

// async global->LDS, 16B per lane; LDS dest is wave-uniform base + lane*16
__device__ __forceinline__ void load_lds16(const uint16_t* g, uint16_t* l) {
  __builtin_amdgcn_global_load_lds(
      (const __attribute__((address_space(1))) void*)(const void*)g,
      (__attribute__((address_space(3))) void*)(void*)l, 16, 0, 0);
}

// ---------------------------------------------------------------------------
// Transpose fp32 [R][C] -> bf16 [C][R]  (B^T weight layout builder)
// ---------------------------------------------------------------------------
struct TD { const float* in; uint16_t* out; };
struct TD14 { TD d[14]; };

__global__ __launch_bounds__(256) void k_transpose(TD14 ds, int R, int C) {
  const float* in = ds.d[blockIdx.y].in;
  uint16_t* out = ds.d[blockIdx.y].out;
  const int nTC = C >> 5;
  const int bi = blockIdx.x / nTC, bj = blockIdx.x % nTC;
  __shared__ float t[32][33];
  const int tx = threadIdx.x & 31, ty = threadIdx.x >> 5;  // ty 0..7
#pragma unroll
  for (int p = 0; p < 4; ++p) {
    int r = bi * 32 + ty + p * 8;
    t[ty + p * 8][tx] = in[(size_t)r * C + bj * 32 + tx];
  }
  __syncthreads();
#pragma unroll
  for (int p = 0; p < 4; ++p) {
    int c = bj * 32 + ty + p * 8;
    out[(size_t)c * R + bi * 32 + tx] = f2bf(t[tx][ty + p * 8]);
  }
}

// plain fp32 -> bf16 convert (error_memory, kept row-major for sim's B^T)
__global__ __launch_bounds__(256) void k_f2bf4(const float* __restrict__ in,
                                               uint16_t* __restrict__ out) {
  int i = (blockIdx.x * 256 + threadIdx.x) * 4;
  float4 v = *(const float4*)(in + i);
  u16x4 o = {f2bf(v.x), f2bf(v.y), f2bf(v.z), f2bf(v.w)};
  *(u16x4*)(out + i) = o;
}

// pack bq|bk|bv (3 scales) into BQKV[3][3072]
__global__ __launch_bounds__(256) void k_biaspack(const float* __restrict__ bq,
                                                  const float* __restrict__ bk,
                                                  const float* __restrict__ bv,
                                                  float* __restrict__ dst) {
  int g = blockIdx.x * 256 + threadIdx.x;  // 9216
  int i = g / 3072, j = g - i * 3072;
  const float* src = (j < 1024)   ? bq + i * 1024 + j
                     : (j < 2048) ? bk + i * 1024 + (j - 1024)
                                  : bv + i * 1024 + (j - 2048);
  dst[g] = *src;
}

// ---------------------------------------------------------------------------
// Downsample x (fp32 [B,2048,1024]) -> bf16 scale-1/2/4 averaged copies
// ---------------------------------------------------------------------------
__global__ __launch_bounds__(256) void k_down(const float* __restrict__ x,
                                              uint16_t* __restrict__ x1,
                                              uint16_t* __restrict__ x2,
                                              uint16_t* __restrict__ x4) {
  int g = blockIdx.x * 256 + threadIdx.x;  // 2*512*1024 threads
  int c = g & 1023;
  int l4 = (g >> 10) & 511;
  int b = g >> 19;
  const float* xp = x + (size_t)(b * 2048 + l4 * 4) * 1024 + c;
  float a0 = xp[0], a1 = xp[1024], a2 = xp[2048], a3 = xp[3072];
  size_t r1 = (size_t)(b * 2048 + l4 * 4) * 1024 + c;
  x1[r1] = f2bf(a0);
  x1[r1 + 1024] = f2bf(a1);
  x1[r1 + 2048] = f2bf(a2);
  x1[r1 + 3072] = f2bf(a3);
  size_t r2 = (size_t)(b * 1024 + l4 * 2) * 1024 + c;
  x2[r2] = f2bf(0.5f * (a0 + a1));
  x2[r2 + 1024] = f2bf(0.5f * (a2 + a3));
  x4[(size_t)(b * 512 + l4) * 1024 + c] = f2bf(0.25f * (a0 + a1 + a2 + a3));
}

// ---------------------------------------------------------------------------
// bf16 GEMM, B^T input layout (BT[n][k]). v = (acc*scale + bias) * post,
// post = qscale for cols < qcols else 1. 128x128 tile, BK=32, 4 waves (2x2).
// ---------------------------------------------------------------------------
__global__ __launch_bounds__(256) void k_gemm(
    const uint16_t* __restrict__ A, const uint16_t* __restrict__ BT,
    const float* __restrict__ bias, void* __restrict__ C, int M, int N, int K,
    int ldc, float scale, float qscale, int qcols, int out_bf16) {
  __shared__ __align__(16) uint16_t Al[128 * 32];
  __shared__ __align__(16) uint16_t Bl[128 * 32];
  const int tid = threadIdx.x;
  const int wave = tid >> 6, lane = tid & 63;
  const int wr = wave >> 1, wc = wave & 1;
  const int lr = lane & 15, lg = lane >> 4;
  const int bM = blockIdx.y * 128, bN = blockIdx.x * 128;
  (void)M; (void)N;

  f32x4 acc[4][4] = {};

  for (int k0 = 0; k0 < K; k0 += 32) {
    __syncthreads();  // previous tile's frag reads done before overwrite
#pragma unroll
    for (int j = 0; j < 2; ++j) {
      int ck = wave * 2 + j;          // 8 chunks of 1024B per tile
      int p = ck * 64 + lane;         // 16B chunk index
      int row = p >> 2, kq = p & 3;
      load_lds16(A + (size_t)(bM + row) * K + k0 + kq * 8, &Al[ck * 512]);
      load_lds16(BT + (size_t)(bN + row) * K + k0 + kq * 8, &Bl[ck * 512]);
    }
    __syncthreads();  // vmcnt(0) drain -> LDS ready
    s16x8 af[4], bfr[4];
#pragma unroll
    for (int i = 0; i < 4; ++i)
      af[i] = *(const s16x8*)&Al[(wr * 64 + i * 16 + lr) * 32 + lg * 8];
#pragma unroll
    for (int i = 0; i < 4; ++i)
      bfr[i] = *(const s16x8*)&Bl[(wc * 64 + i * 16 + lr) * 32 + lg * 8];
#pragma unroll
    for (int i = 0; i < 4; ++i)
#pragma unroll
      for (int jn = 0; jn < 4; ++jn)
        acc[i][jn] = __builtin_amdgcn_mfma_f32_16x16x32_bf16(
            af[i], bfr[jn], acc[i][jn], 0, 0, 0);
  }

  // epilogue: D layout col=lane&15, row=(lane>>4)*4+reg  [m89-verified]
#pragma unroll
  for (int i = 0; i < 4; ++i) {
    int rg = bM + wr * 64 + i * 16 + lg * 4;
#pragma unroll
    for (int jn = 0; jn < 4; ++jn) {
      int cg = bN + wc * 64 + jn * 16 + lr;
      float bv = bias ? bias[cg] : 0.f;
      float post = (cg < qcols) ? qscale : 1.f;
#pragma unroll
      for (int r = 0; r < 4; ++r) {
        float v = (acc[i][jn][r] * scale + bv) * post;
        if (out_bf16)
          ((uint16_t*)C)[(size_t)(rg + r) * ldc + cg] = f2bf(v);
        else
          ((float*)C)[(size_t)(rg + r) * ldc + cg] = v;
      }
    }
  }
}

// ---------------------------------------------------------------------------
// k_gemm64: same math, BM=64 x BN=128 tile (grid 2x denser in M).
// 4 waves (2x2): wave quadrant = 32 rows x 64 cols (2x4 frags).
// Staging: 12 chunks (A:4, B:8), 3 per wave. Epilogue identical semantics.
// ---------------------------------------------------------------------------
__global__ __launch_bounds__(256) void k_gemm64(
    const uint16_t* __restrict__ A, const uint16_t* __restrict__ BT,
    const float* __restrict__ bias, void* __restrict__ C, int M, int N, int K,
    int ldc, float scale, float qscale, int qcols, int out_bf16) {
  __shared__ __align__(16) uint16_t Al[64 * 32];   // 4 KB
  __shared__ __align__(16) uint16_t Bl[128 * 32];  // 8 KB
  const int tid = threadIdx.x;
  const int wave = tid >> 6, lane = tid & 63;
  const int wr = wave >> 1, wc = wave & 1;
  const int lr = lane & 15, lg = lane >> 4;
  const int bM = blockIdx.y * 64, bN = blockIdx.x * 128;
  (void)M; (void)N;

  f32x4 acc[2][4] = {};

  for (int k0 = 0; k0 < K; k0 += 32) {
    __syncthreads();
#pragma unroll
    for (int jj = 0; jj < 3; ++jj) {
      int ck = wave * 3 + jj;         // 0..11: 0-3 A chunks, 4-11 B chunks
      int row16 = lane >> 2, kq = lane & 3;
      if (ck < 4)
        load_lds16(A + (size_t)(bM + ck * 16 + row16) * K + k0 + kq * 8,
                   &Al[ck * 512]);
      else
        load_lds16(BT + (size_t)(bN + (ck - 4) * 16 + row16) * K + k0 + kq * 8,
                   &Bl[(ck - 4) * 512]);
    }
    __syncthreads();
    s16x8 af[2], bfr[4];
#pragma unroll
    for (int i = 0; i < 2; ++i)
      af[i] = *(const s16x8*)&Al[(wr * 32 + i * 16 + lr) * 32 + lg * 8];
#pragma unroll
    for (int i = 0; i < 4; ++i)
      bfr[i] = *(const s16x8*)&Bl[(wc * 64 + i * 16 + lr) * 32 + lg * 8];
#pragma unroll
    for (int i = 0; i < 2; ++i)
#pragma unroll
      for (int jn = 0; jn < 4; ++jn)
        acc[i][jn] = __builtin_amdgcn_mfma_f32_16x16x32_bf16(
            af[i], bfr[jn], acc[i][jn], 0, 0, 0);
  }

#pragma unroll
  for (int i = 0; i < 2; ++i) {
    int rg = bM + wr * 32 + i * 16 + lg * 4;
#pragma unroll
    for (int jn = 0; jn < 4; ++jn) {
      int cg = bN + wc * 64 + jn * 16 + lr;
      float bv = bias ? bias[cg] : 0.f;
      float post = (cg < qcols) ? qscale : 1.f;
#pragma unroll
      for (int r = 0; r < 4; ++r) {
        float v = (acc[i][jn][r] * scale + bv) * post;
        if (out_bf16)
          ((uint16_t*)C)[(size_t)(rg + r) * ldc + cg] = f2bf(v);
        else
          ((float*)C)[(size_t)(rg + r) * ldc + cg] = v;
      }
    }
  }
}

// ---------------------------------------------------------------------------
// V transpose: v bf16 [B*S][ld] (col offset pre-applied) -> vt[(bh)*64+d][S]
// ---------------------------------------------------------------------------
__global__ __launch_bounds__(256) void k_vtrans(const uint16_t* __restrict__ v,
                                                uint16_t* __restrict__ vt,
                                                int S, int ld) {
  const int nKT = S >> 6;
  const int bh = blockIdx.x / nKT, kt = blockIdx.x % nKT;
  const int b = bh >> 4, h = bh & 15;
  __shared__ uint16_t t[64][65];
  for (int i = threadIdx.x; i < 4096; i += 256) {
    int kk = i >> 6, dd = i & 63;
    t[dd][kk] = v[(size_t)(b * S + kt * 64 + kk) * ld + h * 64 + dd];
  }
  __syncthreads();
  for (int i = threadIdx.x; i < 4096; i += 256) {
    int dd = i >> 6, kk = i & 63;
    vt[((size_t)(bh * 64) + dd) * S + kt * 64 + kk] = t[dd][kk];
  }
}

// ---------------------------------------------------------------------------
// Flash attention, LDS-shared K/V (R8-proven). See R8 header comment.
// ---------------------------------------------------------------------------
__global__ __launch_bounds__(256) void k_attn(const uint16_t* __restrict__ qkv,
                                              const uint16_t* __restrict__ vt,
                                              uint16_t* __restrict__ ctx,
                                              int S) {
  __shared__ __align__(16) uint16_t Kl[64 * 64];  // 8 KB
  __shared__ __align__(16) uint16_t Vl[64 * 64];  // 8 KB
  const int lane = threadIdx.x & 63;
  const int wv = threadIdx.x >> 6;
  const int nQB = S >> 7;  // 128 q-rows per block
  const int bh = blockIdx.x / nQB;  // b*16+h
  const int qb = blockIdx.x % nQB;
  const int h = bh & 15, b = bh >> 4;
  const int lr = lane & 15, lg = lane >> 4;

  const int qrow0 = qb * 128 + wv * 32;
  const uint16_t* qp =
      qkv + (size_t)(b * S + qrow0 + lr) * 3072 + h * 64 + lg * 8;
  s16x8 qf0[2], qf1[2];
  qf0[0] = *(const s16x8*)qp;
  qf1[0] = *(const s16x8*)(qp + 32);
  qf0[1] = *(const s16x8*)(qp + 16 * 3072);
  qf1[1] = *(const s16x8*)(qp + 16 * 3072 + 32);
  const uint16_t* kg = qkv + (size_t)(b * S) * 3072 + 1024 + h * 64;
  const uint16_t* vg = vt + (size_t)(bh * 64) * S;

  f32x4 acc[2][4] = {};
  float mS[2] = {-1e30f, -1e30f};
  float lS[2] = {0.f, 0.f};

  const int srl = lane >> 3;                 // row within 8-row chunk
  const int ssl = (lane & 7) ^ (srl & 7);    // pre-swizzled source slot

  const int nKV = S >> 6;
  for (int blk = 0; blk < nKV; ++blk) {
    __syncthreads();
#pragma unroll
    for (int j = 0; j < 4; ++j) {
      int ck = wv * 4 + j;  // 0..15 : 0-7 K chunks, 8-15 V chunks
      int rl = ((ck & 7) << 3) + srl;
      if (ck < 8)
        load_lds16(kg + (size_t)(blk * 64 + rl) * 3072 + ssl * 8,
                   &Kl[(ck & 7) * 512]);
      else
        load_lds16(vg + (size_t)rl * S + blk * 64 + ssl * 8,
                   &Vl[(ck & 7) * 512]);
    }
    __syncthreads();

#pragma unroll
    for (int kt = 0; kt < 4; ++kt) {
      const int r = kt * 16 + lr;
      const int sw = r & 7;
      s16x8 K0 = *(const s16x8*)&Kl[r * 64 + ((lg ^ sw) << 3)];
      s16x8 K1 = *(const s16x8*)&Kl[r * 64 + (((lg + 4) ^ sw) << 3)];
      s16x4 vf[4];
#pragma unroll
      for (int c = 0; c < 4; ++c) {
        int d = c * 16 + lr;
        int s16 = (kt << 1) | (lg >> 1);
        vf[c] = *(const s16x4*)&Vl[d * 64 + (((s16 ^ (d & 7)) << 3) |
                                             ((lg & 1) << 2))];
      }
#pragma unroll
      for (int f = 0; f < 2; ++f) {
        f32x4 st = {};
        st = __builtin_amdgcn_mfma_f32_16x16x32_bf16(K0, qf0[f], st, 0, 0, 0);
        st = __builtin_amdgcn_mfma_f32_16x16x32_bf16(K1, qf1[f], st, 0, 0, 0);
        float tmax = fmaxf(fmaxf(st[0], st[1]), fmaxf(st[2], st[3]));
        tmax = fmaxf(tmax, __shfl_xor(tmax, 16));
        tmax = fmaxf(tmax, __shfl_xor(tmax, 32));
        if (!__all(tmax <= mS[f])) {
          float mn = fmaxf(mS[f], tmax);
          float fac = fexp2(mS[f] - mn);
          mS[f] = mn;
          lS[f] *= fac;
#pragma unroll
          for (int c = 0; c < 4; ++c) acc[f][c] *= fac;
        }
        float p0 = fexp2(st[0] - mS[f]), p1 = fexp2(st[1] - mS[f]);
        float p2 = fexp2(st[2] - mS[f]), p3 = fexp2(st[3] - mS[f]);
        lS[f] += (p0 + p1) + (p2 + p3);
        s16x4 pb;
        pb[0] = (short)f2bf(p0);
        pb[1] = (short)f2bf(p1);
        pb[2] = (short)f2bf(p2);
        pb[3] = (short)f2bf(p3);
#pragma unroll
        for (int c = 0; c < 4; ++c)
          acc[f][c] = __builtin_amdgcn_mfma_f32_16x16x16bf16_1k(
              vf[c], pb, acc[f][c], 0, 0, 0);
      }
    }
  }

#pragma unroll
  for (int f = 0; f < 2; ++f) {
    float l = lS[f];
    l += __shfl_xor(l, 16);
    l += __shfl_xor(l, 32);
    const float inv = 1.f / l;
    uint16_t* crow =
        ctx + (size_t)(b * S + qrow0 + f * 16 + lr) * 1024 + h * 64;
#pragma unroll
    for (int c = 0; c < 4; ++c) {
      u16x4 o;
#pragma unroll
      for (int r = 0; r < 4; ++r) o[r] = f2bf(acc[f][c][r] * inv);
      *(u16x4*)(crow + c * 16 + lg * 4) = o;
    }
  }
}

// ---------------------------------------------------------------------------
// Row softmax over M=1024: sim fp32 [4096][1024] -> weights bf16
// ---------------------------------------------------------------------------
__global__ __launch_bounds__(256) void k_softmax(const float* __restrict__ sim,
                                                 uint16_t* __restrict__ w) {
  __shared__ float red[4];
  const int row = blockIdx.x, t = threadIdx.x;
  const size_t base = (size_t)row * 1024 + t * 4;
  float4 v = *(const float4*)(sim + base);
  float mx = fmaxf(fmaxf(v.x, v.y), fmaxf(v.z, v.w));
#pragma unroll
  for (int o = 32; o > 0; o >>= 1) mx = fmaxf(mx, __shfl_xor(mx, o));
  if ((t & 63) == 0) red[t >> 6] = mx;
  __syncthreads();
  mx = fmaxf(fmaxf(red[0], red[1]), fmaxf(red[2], red[3]));
  __syncthreads();
  float p0 = __expf(v.x - mx), p1 = __expf(v.y - mx);
  float p2 = __expf(v.z - mx), p3 = __expf(v.w - mx);
  float s = p0 + p1 + p2 + p3;
#pragma unroll
  for (int o = 32; o > 0; o >>= 1) s += __shfl_xor(s, o);
  if ((t & 63) == 0) red[t >> 6] = s;
  __syncthreads();
  s = red[0] + red[1] + red[2] + red[3];
  float inv = 1.f / s;
  u16x4 o = {f2bf(p0 * inv), f2bf(p1 * inv), f2bf(p2 * inv), f2bf(p3 * inv)};
  *(u16x4*)(w + base) = o;
}

// ---------------------------------------------------------------------------
// Upsample scores2/scores4 into Acf columns 1024..3071 (bf16)
// ---------------------------------------------------------------------------
__global__ __launch_bounds__(256) void k_upsample(const uint16_t* __restrict__ s2,
                                                  const uint16_t* __restrict__ s4,
                                                  uint16_t* __restrict__ acf) {
  int g = blockIdx.x * 256 + threadIdx.x;  // 4096 rows * 256 groups
  int cg = g & 255;
  int row = g >> 8;
  int b = row >> 11, l = row & 2047;
  int c = cg * 8;
  const uint16_t* src =
      (c < 1024) ? s2 + (size_t)(b * 1024 + (l >> 1)) * 1024 + c
                 : s4 + (size_t)(b * 512 + (l >> 2)) * 1024 + (c - 1024);
  *(s16x8*)(acf + (size_t)row * 4096 + 1024 + c) = *(const s16x8*)src;
}

// ---------------------------------------------------------------------------
// Final: LayerNorm(cf)+ReLU, gate=sigmoid(gl), confidence, residual.
// ---------------------------------------------------------------------------
__global__ __launch_bounds__(256) void k_final(
    const float* __restrict__ cf, const float* __restrict__ gl,
    const float* __restrict__ x, const float* __restrict__ lns,
    const float* __restrict__ lnb, float* __restrict__ out) {
  __shared__ float red[4];
  const int row = blockIdx.x, t = threadIdx.x;
  const size_t base = (size_t)row * 1024 + t * 4;
  float4 cv = *(const float4*)(cf + base);
  float4 gv = *(const float4*)(gl + base);
  float g0 = 1.f / (1.f + __expf(-gv.x));
  float g1 = 1.f / (1.f + __expf(-gv.y));
  float g2 = 1.f / (1.f + __expf(-gv.z));
  float g3 = 1.f / (1.f + __expf(-gv.w));

  auto bsum = [&](float v) -> float {
#pragma unroll
    for (int o = 32; o > 0; o >>= 1) v += __shfl_xor(v, o);
    if ((t & 63) == 0) red[t >> 6] = v;
    __syncthreads();
    float r = red[0] + red[1] + red[2] + red[3];
    __syncthreads();
    return r;
  };
  float mu = bsum(cv.x + cv.y + cv.z + cv.w) * (1.f / 1024.f);
  float conf = bsum(g0 + g1 + g2 + g3) * (1.f / 1024.f);
  float d0 = cv.x - mu, d1 = cv.y - mu, d2 = cv.z - mu, d3 = cv.w - mu;
  float var = bsum(d0 * d0 + d1 * d1 + d2 * d2 + d3 * d3) * (1.f / 1024.f);
  float rstd = rsqrtf(var + 1e-6f);
  float4 ls = *(const float4*)(lns + t * 4);
  float4 lb = *(const float4*)(lnb + t * 4);
  float y0 = fmaxf(d0 * rstd * ls.x + lb.x, 0.f);
  float y1 = fmaxf(d1 * rstd * ls.y + lb.y, 0.f);
  float y2 = fmaxf(d2 * rstd * ls.z + lb.z, 0.f);
  float y3 = fmaxf(d3 * rstd * ls.w + lb.w, 0.f);
  float sc = sqrtf(1.f / (1024.f * conf + 1e-6f));
  float4 xv = *(const float4*)(x + base);
  float4 o1 = {xv.x + sc * g0 * y0, xv.y + sc * g1 * y1, xv.z + sc * g2 * y2,
               xv.w + sc * g3 * y3};
  *(float4*)(out + base) = o1;
  float4 o2 = {g0, g1, g2, g3};
  *(float4*)(out + 4194304 + base) = o2;
}

// ---------------------------------------------------------------------------
// Workspace layout (bytes)
// ---------------------------------------------------------------------------
static constexpr size_t OFF_QKVT = 0;            // 3 scales x 6 MiB (Wq|Wk|Wv)^T
static constexpr size_t OFF_WOT = 18 * MiBc;     // 3 x 2 MiB
static constexpr size_t OFF_W1T = 24 * MiBc;     // 8
static constexpr size_t OFF_W2T = 32 * MiBc;     // 2
static constexpr size_t OFF_EMB = 34 * MiBc;     // 2
static constexpr size_t OFF_EMT = 36 * MiBc;     // 2
static constexpr size_t OFF_XB1 = 38 * MiBc;     // 8
static constexpr size_t OFF_XB2 = 46 * MiBc;     // 4
static constexpr size_t OFF_XB4 = 50 * MiBc;     // 2
static constexpr size_t OFF_QKV = 52 * MiBc;     // 24 (reused per scale)
static constexpr size_t OFF_VT  = 76 * MiBc;     // 8
static constexpr size_t OFF_CTX = 84 * MiBc;     // 8
static constexpr size_t OFF_S2  = 92 * MiBc;     // 4
static constexpr size_t OFF_S4  = 96 * MiBc;     // 2
static constexpr size_t OFF_ACF = 98 * MiBc;     // 32
static constexpr size_t OFF_SIM = 130 * MiBc;    // 16 (fp32)
static constexpr size_t OFF_WSM = 146 * MiBc;    // 8
static constexpr size_t OFF_CF  = 154 * MiBc;    // 16 (fp32)
static constexpr size_t OFF_BQKV = 170 * MiBc;   // 36 KB (gate logits in d_out)
static constexpr size_t WS_NEED = 186 * MiBc;

static constexpr float QSC = 0.125f * 1.44269504f;  // 1/sqrt(64) * log2(e)

extern "C" void kernel_launch(void* const* d_in, const int* in_sizes, int n_in,
                              void* d_out, int out_size, void* d_ws,
                              size_t ws_size, hipStream_t stream) {
  (void)in_sizes; (void)n_in; (void)out_size;
  const float* x  = (const float*)d_in[0];
  const float* em = (const float*)d_in[1];
  const float* Wq = (const float*)d_in[2];
  const float* bq = (const float*)d_in[3];
  const float* Wk = (const float*)d_in[4];
  const float* bk = (const float*)d_in[5];
  const float* Wv = (const float*)d_in[6];
  const float* bv = (const float*)d_in[7];
  const float* Wo = (const float*)d_in[8];
  const float* bo = (const float*)d_in[9];
  const float* W1 = (const float*)d_in[10];
  const float* b1 = (const float*)d_in[11];
  const float* lns = (const float*)d_in[12];
  const float* lnb = (const float*)d_in[13];
  const float* W2 = (const float*)d_in[14];
  const float* b2 = (const float*)d_in[15];
  float* out = (float*)d_out;

  if (ws_size < WS_NEED) {  // sentinel: makes ws-too-small distinguishable
    hipMemsetAsync(d_out, 0x7f, 4, stream);
    return;
  }
  uint8_t* w8 = (uint8_t*)d_ws;
  auto U16 = [&](size_t off) { return (uint16_t*)(w8 + off); };
  uint16_t* QKVT = U16(OFF_QKVT);
  uint16_t* WOT = U16(OFF_WOT);
  uint16_t* W1T = U16(OFF_W1T);
  uint16_t* W2T = U16(OFF_W2T);
  uint16_t* EMB = U16(OFF_EMB);
  uint16_t* EMT = U16(OFF_EMT);
  uint16_t* XB1 = U16(OFF_XB1);
  uint16_t* XB2 = U16(OFF_XB2);
  uint16_t* XB4 = U16(OFF_XB4);
  uint16_t* QKVb = U16(OFF_QKV);
  uint16_t* VTb = U16(OFF_VT);
  uint16_t* CTX = U16(OFF_CTX);
  uint16_t* S2b = U16(OFF_S2);
  uint16_t* S4b = U16(OFF_S4);
  uint16_t* ACF = U16(OFF_ACF);
  float* SIM = (float*)(w8 + OFF_SIM);
  uint16_t* WSM = U16(OFF_WSM);
  float* CF = (float*)(w8 + OFF_CF);
  float* BQKV = (float*)(w8 + OFF_BQKV);
  float* GL = out + 4194304;  // gate logits in-place in d_out gate region

  const size_t MM = 1024 * 1024;
  const size_t SC3 = 3 * MM;  // elements per packed QKV^T scale

  // 1) weight prep: transposes to B^T layout (QKV packed), EM bf16, biases
  TD14 td{};
  for (int i = 0; i < 3; ++i) {
    td.d[i]     = {Wq + (size_t)i * MM, QKVT + (size_t)i * SC3};
    td.d[3 + i] = {Wk + (size_t)i * MM, QKVT + (size_t)i * SC3 + MM};
    td.d[6 + i] = {Wv + (size_t)i * MM, QKVT + (size_t)i * SC3 + 2 * MM};
    td.d[9 + i] = {Wo + (size_t)i * MM, WOT + (size_t)i * MM};
  }
  td.d[12] = {W2, W2T};
  td.d[13] = {em, EMT};
  k_transpose<<<dim3(1024, 14), 256, 0, stream>>>(td, 1024, 1024);
  TD14 t1{};
  t1.d[0] = {W1, W1T};
  k_transpose<<<dim3(4096, 1), 256, 0, stream>>>(t1, 4096, 1024);
  k_f2bf4<<<dim3(1024), 256, 0, stream>>>(em, EMB);
  k_biaspack<<<dim3(36), 256, 0, stream>>>(bq, bk, bv, BQKV);
  k_down<<<dim3(4096), 256, 0, stream>>>(x, XB1, XB2, XB4);

  // 2) per-scale self-attention (merged QKV GEMM, N=3072; Q cols post-scaled
  //    by QSC -> exp2 domain). s0 QKV keeps 128^2 (grid 768); s1/s2 use BM=64.
  for (int i = 0; i < 3; ++i) {
    const int S = 2048 >> i;
    const int R = 2 * S;
    const uint16_t* xb = (i == 0) ? XB1 : (i == 1) ? XB2 : XB4;
    if (i == 0)
      k_gemm<<<dim3(24, R / 128), 256, 0, stream>>>(
          xb, QKVT, BQKV, QKVb, R, 3072, 1024, 3072, 1.f, QSC, 1024, 1);
    else
      k_gemm64<<<dim3(24, R / 64), 256, 0, stream>>>(
          xb, QKVT + (size_t)i * SC3, BQKV + i * 3072, QKVb, R, 3072, 1024,
          3072, 1.f, QSC, 1024, 1);
    k_vtrans<<<dim3(32 * (S / 64)), 256, 0, stream>>>(QKVb + 2048, VTb, S, 3072);
    k_attn<<<dim3(32 * (S / 128)), 256, 0, stream>>>(QKVb, VTb, CTX, S);
    dim3 gg(8, R / 64);
    if (i == 0)
      k_gemm64<<<gg, 256, 0, stream>>>(CTX, WOT, bo, ACF, R, 1024, 1024, 4096,
                                       1.f, 1.f, 0, 1);
    else if (i == 1)
      k_gemm64<<<gg, 256, 0, stream>>>(CTX, WOT + MM, bo + 1024, S2b, R, 1024,
                                       1024, 1024, 1.f, 1.f, 0, 1);
    else
      k_gemm64<<<gg, 256, 0, stream>>>(CTX, WOT + 2 * MM, bo + 2048, S4b, R,
                                       1024, 1024, 1024, 1.f, 1.f, 0, 1);
  }

  // 3) memory path: sim -> softmax -> readback (into Acf cols 3072..4095)
  k_gemm64<<<dim3(8, 64), 256, 0, stream>>>(XB1, EMB, nullptr, SIM, 4096, 1024,
                                            1024, 1024, 0.03125f, 1.f, 0, 0);
  k_softmax<<<dim3(4096), 256, 0, stream>>>(SIM, WSM);
  k_gemm64<<<dim3(8, 64), 256, 0, stream>>>(WSM, EMT, nullptr, ACF + 3072, 4096,
                                            1024, 1024, 4096, 1.f, 1.f, 0, 1);
  k_upsample<<<dim3(4096), 256, 0, stream>>>(S2b, S4b, ACF);

  // 4) cf GEMM (K=4096), gate GEMM, fused LN/gate/residual
  k_gemm64<<<dim3(8, 64), 256, 0, stream>>>(ACF, W1T, b1, CF, 4096, 1024, 4096,
                                            1024, 1.f, 1.f, 0, 0);
  k_gemm64<<<dim3(8, 64), 256, 0, stream>>>(XB1, W2T, b2, GL, 4096, 1024, 1024,
                                            1024, 1.f, 1.f, 0, 0);
  k_final<<<dim3(4096), 256, 0, stream>>>(CF, GL, x, lns, lnb, out);
}